// Round 6
// baseline (6685.944 us; speedup 1.0000x reference)
//
#include <hip/hip_runtime.h>
#include <hip/hip_bf16.h>

using bf16 = __hip_bfloat16;
using short8  = __attribute__((ext_vector_type(8))) short;
using floatx4 = __attribute__((ext_vector_type(4))) float;

static __device__ __forceinline__ float b2f(bf16 v){ return __bfloat162float(v); }
static __device__ __forceinline__ float toF(float v){ return v; }
static __device__ __forceinline__ float toF(bf16 v){ return __bfloat162float(v); }
// dtype-adaptive input load: f32 flag selects interpretation; i is ELEMENT index
static __device__ __forceinline__ float ld(const void* p, size_t i, int f32){
  return f32 ? ((const float*)p)[i] : __bfloat162float(((const bf16*)p)[i]);
}
static __device__ __forceinline__ short f2bf(float f){
  bf16 h = __float2bfloat16(f);
  return *reinterpret_cast<short*>(&h);
}
static __device__ __forceinline__ short abits(float f){ return f2bf(f); }
static __device__ __forceinline__ short abits(bf16 h){ return *reinterpret_cast<short*>(&h); }

constexpr int Bn = 4, Np = 1024, Gn = 128, Kn = 32;
constexpr int DM = 384, DEPTH = 12, CLSn = 40;
constexpr int DI = 768, DSt = 16, DTR = 24;
constexpr int Ln = 384;
constexpr int NCH = 12, CHS = 32;      // scan: 12 chunks x 32 steps
constexpr float EPSf = 1e-5f;
constexpr float BNS = 0.99999500003749968752f; // 1/sqrt(1+1e-5)
constexpr float LOG2E = 1.4426950408889634f;

// ---------------------------------------------------------------- dtype detector
__global__ __launch_bounds__(64) void detect_kernel(const void* __restrict__ pts,
                                                    int* __restrict__ flag){
  int t = threadIdx.x;
  const bf16* p = (const bf16*)pts;
  float m = 0.f;
  for (int i = t; i < 256; i += 64){
    float v = fabsf(b2f(p[i]));
    if (!(v <= 1e6f)) m = 1e30f;
    else m = fmaxf(m, v);
  }
  #pragma unroll
  for (int o = 32; o > 0; o >>= 1) m = fmaxf(m, __shfl_down(m, o));
  if (t == 0) flag[0] = (m > 1e6f) ? 1 : 0;   // 1 = fp32 data
}

// ---------------------------------------------------------------- FPS (single wave)
// _rn distance math, order dx*dx+dy*dy+dz*dz; argmax first-index tie-break.
__global__ __launch_bounds__(64) void fps_kernel(const void* __restrict__ pts,
                                                 float* __restrict__ center,
                                                 const int* __restrict__ dflag){
  const int f32 = *dflag;
  int b = blockIdx.x;
  __shared__ float xs[1024], ys[1024], zs[1024];
  int t = threadIdx.x;
  size_t base = (size_t)b * Np * 3;
  float dmin[16];
  #pragma unroll
  for (int i = 0; i < 16; ++i){
    int n = t + 64*i;
    xs[n] = ld(pts, base + n*3+0, f32);
    ys[n] = ld(pts, base + n*3+1, f32);
    zs[n] = ld(pts, base + n*3+2, f32);
    dmin[i] = 1e10f;
  }
  if (t == 0){
    center[(size_t)(b*Gn)*3+0] = xs[0];
    center[(size_t)(b*Gn)*3+1] = ys[0];
    center[(size_t)(b*Gn)*3+2] = zs[0];
  }
  int last = 0;
  for (int it = 1; it < Gn; ++it){
    float px = xs[last], py = ys[last], pz = zs[last];
    float v = -1.f; int idx = 0;
    #pragma unroll
    for (int i = 0; i < 16; ++i){
      int n = t + 64*i;
      float dx = __fsub_rn(xs[n], px);
      float dy = __fsub_rn(ys[n], py);
      float dz = __fsub_rn(zs[n], pz);
      float d  = __fadd_rn(__fadd_rn(__fmul_rn(dx,dx), __fmul_rn(dy,dy)), __fmul_rn(dz,dz));
      float dm = fminf(dmin[i], d); dmin[i] = dm;
      if (dm > v){ v = dm; idx = n; }   // n increases with i: first-index on ties
    }
    #pragma unroll
    for (int o = 32; o > 0; o >>= 1){
      float v2 = __shfl_down(v, o); int i2 = __shfl_down(idx, o);
      if (v2 > v || (v2 == v && i2 < idx)){ v = v2; idx = i2; }
    }
    idx = __shfl(idx, 0);
    idx = min(max(idx, 0), Np-1);       // address-safety clamp
    if (t == 0){
      center[(size_t)(b*Gn+it)*3+0] = xs[idx];
      center[(size_t)(b*Gn+it)*3+1] = ys[idx];
      center[(size_t)(b*Gn+it)*3+2] = zs[idx];
    }
    last = idx;
  }
}

// ---------------------------------------------------------------- KNN
__global__ __launch_bounds__(256) void knn_kernel(const void* __restrict__ pts,
                                                  const float* __restrict__ center,
                                                  float* __restrict__ nb,
                                                  const int* __restrict__ dflag){
  const int f32 = *dflag;
  int gid = blockIdx.x; int b = gid >> 7;
  __shared__ float d2[1024];
  __shared__ float rv[4]; __shared__ int ri[4];
  int t = threadIdx.x;
  float cx = center[(size_t)gid*3+0], cy = center[(size_t)gid*3+1], cz = center[(size_t)gid*3+2];
  size_t base = (size_t)b * Np * 3;
  for (int n = t; n < Np; n += 256){
    float dx = __fsub_rn(cx, ld(pts, base + n*3+0, f32));
    float dy = __fsub_rn(cy, ld(pts, base + n*3+1, f32));
    float dz = __fsub_rn(cz, ld(pts, base + n*3+2, f32));
    d2[n] = __fadd_rn(__fadd_rn(__fmul_rn(dx,dx), __fmul_rn(dy,dy)), __fmul_rn(dz,dz));
  }
  __syncthreads();
  for (int kk = 0; kk < Kn; ++kk){
    float v = 3e38f; int idx = 0;
    for (int n = t; n < Np; n += 256){
      float d = d2[n];
      if (d < v || (d == v && n < idx)){ v = d; idx = n; }
    }
    #pragma unroll
    for (int o = 32; o > 0; o >>= 1){
      float v2 = __shfl_down(v, o); int i2 = __shfl_down(idx, o);
      if (v2 < v || (v2 == v && i2 < idx)){ v = v2; idx = i2; }
    }
    if ((t & 63) == 0){ rv[t>>6] = v; ri[t>>6] = idx; }
    __syncthreads();
    if (t == 0){
      float bv = rv[0]; int bi = ri[0];
      for (int w = 1; w < 4; ++w){
        if (rv[w] < bv || (rv[w] == bv && ri[w] < bi)){ bv = rv[w]; bi = ri[w]; }
      }
      bi = min(max(bi, 0), Np-1);
      nb[((size_t)gid*Kn+kk)*3+0] = __fsub_rn(ld(pts, base + bi*3+0, f32), cx);
      nb[((size_t)gid*Kn+kk)*3+1] = __fsub_rn(ld(pts, base + bi*3+1, f32), cy);
      nb[((size_t)gid*Kn+kk)*3+2] = __fsub_rn(ld(pts, base + bi*3+2, f32), cz);
      d2[bi] = 3e38f;
    }
    __syncthreads();
  }
}

// ---------------------------------------------------------------- MFMA GEMM
// C[M,N] = act(A[M,K](lda) @ W[N,K]^T + bias). bf16 MFMA, fp32 accumulate.
// 64x64 tile / block; 4 waves; wave w owns rows [w*16, w*16+16) x 64 cols.
// Verified layouts: A[m=lane&15][k=(lane>>4)*8+j]; B[n=lane&15][k]; D col=lane&15,
// row=(lane>>4)*4+reg. LDS row stride 40 shorts (80B: 16B-aligned, <=2-way banks).
template<typename AT, int ACT>
__global__ __launch_bounds__(256) void gemm_mfma(const AT* __restrict__ A, int lda,
                                                 const void* __restrict__ W, size_t wOff,
                                                 const void* __restrict__ bias, size_t bOff,
                                                 const void* __restrict__ g,
                                                 const void* __restrict__ bb,
                                                 float* __restrict__ C, int ldc,
                                                 int M, int N, int K,
                                                 const int* __restrict__ dflag){
  const int f32 = *dflag;
  __shared__ __align__(16) short As[64*40];
  __shared__ __align__(16) short Ws[64*40];
  int bm = blockIdx.x * 64, bn = blockIdx.y * 64;
  int t = threadIdx.x;
  int row = t >> 2;            // 0..63 staging row
  int kseg = (t & 3) * 8;      // 0,8,16,24
  int w = t >> 6, lane = t & 63, m16 = lane & 15, q = lane >> 4;
  floatx4 acc[4] = {};
  for (int k0 = 0; k0 < K; k0 += 32){
    {
      const AT* Ar = A + (size_t)(bm + row)*lda;
      #pragma unroll
      for (int j = 0; j < 8; ++j){
        int k = k0 + kseg + j;
        As[row*40 + kseg + j] = (k < K) ? abits(Ar[k]) : (short)0;
      }
    }
    {
      int n = bn + row;
      #pragma unroll
      for (int j = 0; j < 8; ++j){
        int k = k0 + kseg + j;
        short v = 0;
        if (n < N && k < K) v = f2bf(ld(W, wOff + (size_t)n*K + k, f32));
        Ws[row*40 + kseg + j] = v;
      }
    }
    __syncthreads();
    short8 af = *(const short8*)&As[(w*16 + m16)*40 + q*8];
    #pragma unroll
    for (int j = 0; j < 4; ++j){
      short8 bfr = *(const short8*)&Ws[(j*16 + m16)*40 + q*8];
      acc[j] = __builtin_amdgcn_mfma_f32_16x16x32_bf16(af, bfr, acc[j], 0, 0, 0);
    }
    __syncthreads();
  }
  #pragma unroll
  for (int j = 0; j < 4; ++j){
    int n = bn + j*16 + m16;
    if (n < N){
      float bv = bias ? ld(bias, bOff + n, f32) : 0.f;
      float gv = 0.f, bbv = 0.f;
      if (ACT == 1){ gv = ld(g, n, f32) * BNS; bbv = ld(bb, n, f32); }
      #pragma unroll
      for (int r = 0; r < 4; ++r){
        int m = bm + w*16 + q*4 + r;
        float v = acc[j][r] + bv;
        if (ACT == 1){ v = v * gv + bbv; v = fmaxf(v, 0.f); }
        C[(size_t)m*ldc + n] = v;
      }
    }
  }
}

// -------------------------------------------------- encoder max-pools
__global__ __launch_bounds__(256) void maxk_fg(float* __restrict__ f3in){
  int gg = blockIdx.x; int c = threadIdx.x;
  float m = -3e38f;
  for (int k = 0; k < Kn; ++k) m = fmaxf(m, f3in[((size_t)gg*Kn + k)*512 + 256 + c]);
  for (int k = 0; k < Kn; ++k) f3in[((size_t)gg*Kn + k)*512 + c] = m;
}

__global__ __launch_bounds__(384) void maxk_tok(const float* __restrict__ f4, float* __restrict__ tok){
  int gg = blockIdx.x; int c = threadIdx.x;
  float m = -3e38f;
  for (int k = 0; k < Kn; ++k) m = fmaxf(m, f4[((size_t)gg*Kn + k)*DM + c]);
  tok[(size_t)gg*DM + c] = m;
}

// -------------------------------------------------- pos embedding (adds into tok)
__global__ __launch_bounds__(128) void pos_kernel(const float* __restrict__ center,
                                                  const void* __restrict__ w1, const void* __restrict__ b1,
                                                  const void* __restrict__ w2, const void* __restrict__ b2,
                                                  float* __restrict__ tok,
                                                  const int* __restrict__ dflag){
  const int f32 = *dflag;
  int gid = blockIdx.x;
  __shared__ float h1[128]; __shared__ float c3[3];
  int t = threadIdx.x;
  if (t < 3) c3[t] = center[(size_t)gid*3 + t];
  __syncthreads();
  float a = ld(w1,t*3+0,f32)*c3[0] + ld(w1,t*3+1,f32)*c3[1] + ld(w1,t*3+2,f32)*c3[2] + ld(b1,t,f32);
  h1[t] = 0.5f * a * (1.f + erff(a * 0.70710678118654752440f));
  __syncthreads();
  for (int c = t; c < DM; c += 128){
    float s = ld(b2, c, f32);
    for (int j = 0; j < 128; ++j) s += ld(w2, (size_t)c*128 + j, f32) * h1[j];
    tok[(size_t)gid*DM + c] += s;
  }
}

// -------------------------------------------------- stable argsort (rank count)
__global__ __launch_bounds__(128) void sort_kernel(const float* __restrict__ center,
                                                   int* __restrict__ order){
  int bax = blockIdx.x; int b = bax / 3, ax = bax % 3;
  __shared__ float key[128];
  int t = threadIdx.x;
  key[t] = center[(size_t)(b*Gn + t)*3 + ax];
  __syncthreads();
  float kt = key[t]; int r = 0;
  for (int j = 0; j < Gn; ++j){
    float kj = key[j];
    r += (kj < kt || (kj == kt && j < t)) ? 1 : 0;
  }
  r = min(max(r, 0), Gn-1);
  order[b*Ln + ax*Gn + r] = t;
}

// -------------------------------------------------- token gather + res init
__global__ __launch_bounds__(256) void build_h(const float* __restrict__ tok,
                        const int* __restrict__ order,
                        float* __restrict__ h, float* __restrict__ res){
  int i = blockIdx.x * blockDim.x + threadIdx.x;
  if (i >= Bn*Ln*DM) return;
  int c = i % DM; int l = (i / DM) % Ln; int b = i / (DM*Ln);
  int src = order[b*Ln + l];
  src = min(max(src, 0), Gn-1);
  h[i] = tok[((size_t)(b*Gn + src))*DM + c];
  res[i] = 0.f;
}

// -------------------------------------------------- res += h; x = LN(res)*w+b (bf16 out)
__global__ __launch_bounds__(256) void ln_res_kernel(const float* __restrict__ h,
                                                     float* __restrict__ res,
                                                     bf16* __restrict__ x,
                                                     const void* __restrict__ w, size_t wOff,
                                                     const void* __restrict__ bias,
                                                     const int* __restrict__ dflag){
  const int f32 = *dflag;
  int wv = threadIdx.x >> 6, ln = threadIdx.x & 63;
  int tokid = blockIdx.x*4 + wv;
  const float* hr = h + (size_t)tokid*DM;
  float* rr = res + (size_t)tokid*DM;
  bf16* xr = x + (size_t)tokid*DM;
  float v[6]; float s = 0.f;
  #pragma unroll
  for (int i = 0; i < 6; ++i){ int c = ln + 64*i; float t = hr[c] + rr[c]; rr[c] = t; v[i] = t; s += t; }
  #pragma unroll
  for (int o = 32; o > 0; o >>= 1) s += __shfl_xor(s, o);
  float mu = s * (1.f/DM);
  float q = 0.f;
  #pragma unroll
  for (int i = 0; i < 6; ++i){ float d = v[i] - mu; q += d*d; }
  #pragma unroll
  for (int o = 32; o > 0; o >>= 1) q += __shfl_xor(q, o);
  float rstd = rsqrtf(q * (1.f/DM) + EPSf);
  #pragma unroll
  for (int i = 0; i < 6; ++i){ int c = ln + 64*i;
    xr[c] = __float2bfloat16((v[i]-mu)*rstd*ld(w, wOff+c, f32) + ld(bias, wOff+c, f32)); }
}

// -------------------------------------------------- causal depthwise conv + silu
__global__ __launch_bounds__(256) void conv_kernel(float* __restrict__ xz,
                                                   const void* __restrict__ cw, size_t cwOff,
                                                   const void* __restrict__ cb, size_t cbOff,
                                                   const int* __restrict__ dflag){
  const int f32 = *dflag;
  int id = blockIdx.x * 256 + threadIdx.x;
  int b = id / DI, d = id % DI;
  float w0 = ld(cw, cwOff + d*4+0, f32), w1 = ld(cw, cwOff + d*4+1, f32);
  float w2 = ld(cw, cwOff + d*4+2, f32), w3 = ld(cw, cwOff + d*4+3, f32);
  float bias = ld(cb, cbOff + d, f32);
  float* p = xz + (size_t)b*Ln*1536 + d;
  float u0 = 0.f, u1 = 0.f, u2 = 0.f;
  for (int c0 = 0; c0 < Ln; c0 += 16){
    float r[16];
    #pragma unroll
    for (int i = 0; i < 16; ++i) r[i] = p[(size_t)(c0+i)*1536];
    float o[16];
    #pragma unroll
    for (int i = 0; i < 16; ++i){
      float v = u0*w0 + u1*w1 + u2*w2 + r[i]*w3 + bias;
      o[i] = v / (1.f + expf(-v));
      u0 = u1; u1 = u2; u2 = r[i];
    }
    #pragma unroll
    for (int i = 0; i < 16; ++i) p[(size_t)(c0+i)*1536] = o[i];
  }
}

// -------------------------------------------------- chunked selective scan
__global__ __launch_bounds__(256) void scanA_kernel(const float* __restrict__ xz,
                                                    const float* __restrict__ xdb,
                                                    const void* __restrict__ dpw, size_t dpwOff,
                                                    const void* __restrict__ dpb, size_t dpbOff,
                                                    const void* __restrict__ A_log, size_t AlOff,
                                                    float* __restrict__ SB_S,
                                                    float* __restrict__ SB_dt,
                                                    const int* __restrict__ dflag){
  const int f32 = *dflag;
  __shared__ float sRow[CHS*56];
  int blk = blockIdx.x;
  int c = blk % NCH; int bd = blk / NCH; int dch = bd % 3; int b = bd / 3;
  int t = threadIdx.x; int d = dch*256 + t;
  int l0 = c*CHS;
  for (int i = t; i < CHS*56; i += 256) sRow[i] = xdb[((size_t)(b*Ln + l0))*56 + i];
  const float* xzu = xz + ((size_t)b*Ln)*1536 + d;
  float u[CHS];
  #pragma unroll
  for (int i = 0; i < CHS; ++i) u[i] = xzu[(size_t)(l0+i)*1536];
  float w[DTR];
  #pragma unroll
  for (int j = 0; j < DTR; ++j) w[j] = ld(dpw, dpwOff + (size_t)d*DTR + j, f32);
  float a2[DSt], h[DSt];
  #pragma unroll
  for (int s = 0; s < DSt; ++s){ a2[s] = -expf(ld(A_log, AlOff + (size_t)d*DSt + s, f32)) * LOG2E; h[s] = 0.f; }
  float dbias = ld(dpb, dpbOff + d, f32);
  float sumdt = 0.f;
  __syncthreads();
  #pragma unroll
  for (int i = 0; i < CHS; ++i){
    const float* row = &sRow[i*56];
    float dtr = dbias;
    #pragma unroll
    for (int j = 0; j < DTR; ++j) dtr += w[j] * row[j];
    float dtv = fmaxf(dtr, 0.f) + log1pf(expf(-fabsf(dtr)));
    sumdt += dtv;
    float du = dtv * u[i];
    #pragma unroll
    for (int s = 0; s < DSt; ++s)
      h[s] = exp2f(dtv * a2[s]) * h[s] + du * row[24 + s];
  }
  size_t sb = ((size_t)blk*256 + t)*16;
  #pragma unroll
  for (int s = 0; s < DSt; ++s) SB_S[sb + s] = h[s];
  SB_dt[(size_t)blk*256 + t] = sumdt;
}

__global__ __launch_bounds__(256) void scanC_kernel(float* __restrict__ SB_S,
                                                    const float* __restrict__ SB_dt,
                                                    const void* __restrict__ A_log, size_t AlOff,
                                                    const int* __restrict__ dflag){
  const int f32 = *dflag;
  int id = blockIdx.x*256 + threadIdx.x;
  int t = id & 255; int bd = id >> 8;
  int d = (bd % 3)*256 + t;
  float a2[DSt];
  #pragma unroll
  for (int s = 0; s < DSt; ++s) a2[s] = -expf(ld(A_log, AlOff + (size_t)d*DSt + s, f32)) * LOG2E;
  float h[DSt];
  #pragma unroll
  for (int s = 0; s < DSt; ++s) h[s] = 0.f;
  for (int c = 0; c < NCH; ++c){
    size_t base = (((size_t)bd*NCH + c)*256 + t)*16;
    float sd = SB_dt[((size_t)bd*NCH + c)*256 + t];
    #pragma unroll
    for (int s = 0; s < DSt; ++s){
      float S = SB_S[base + s];
      SB_S[base + s] = h[s];
      h[s] = exp2f(sd * a2[s]) * h[s] + S;
    }
  }
}

__global__ __launch_bounds__(256) void scanB_kernel(float* __restrict__ xz,
                                                    const float* __restrict__ xdb,
                                                    const void* __restrict__ dpw, size_t dpwOff,
                                                    const void* __restrict__ dpb, size_t dpbOff,
                                                    const void* __restrict__ A_log, size_t AlOff,
                                                    const void* __restrict__ Dp, size_t DpOff,
                                                    const float* __restrict__ SB_S,
                                                    const int* __restrict__ dflag){
  const int f32 = *dflag;
  __shared__ float sRow[CHS*56];
  int blk = blockIdx.x;
  int c = blk % NCH; int bd = blk / NCH; int dch = bd % 3; int b = bd / 3;
  int t = threadIdx.x; int d = dch*256 + t;
  int l0 = c*CHS;
  for (int i = t; i < CHS*56; i += 256) sRow[i] = xdb[((size_t)(b*Ln + l0))*56 + i];
  float* xzu = xz + ((size_t)b*Ln)*1536 + d;
  float u[CHS], z[CHS];
  #pragma unroll
  for (int i = 0; i < CHS; ++i){
    u[i] = xzu[(size_t)(l0+i)*1536];
    z[i] = xzu[(size_t)(l0+i)*1536 + DI];
  }
  float w[DTR];
  #pragma unroll
  for (int j = 0; j < DTR; ++j) w[j] = ld(dpw, dpwOff + (size_t)d*DTR + j, f32);
  float a2[DSt], h[DSt];
  #pragma unroll
  for (int s = 0; s < DSt; ++s) a2[s] = -expf(ld(A_log, AlOff + (size_t)d*DSt + s, f32)) * LOG2E;
  size_t sb = ((size_t)blk*256 + t)*16;
  #pragma unroll
  for (int s = 0; s < DSt; ++s) h[s] = SB_S[sb + s];
  float dbias = ld(dpb, dpbOff + d, f32);
  float Dd = ld(Dp, DpOff + d, f32);
  __syncthreads();
  #pragma unroll
  for (int i = 0; i < CHS; ++i){
    const float* row = &sRow[i*56];
    float dtr = dbias;
    #pragma unroll
    for (int j = 0; j < DTR; ++j) dtr += w[j] * row[j];
    float dtv = fmaxf(dtr, 0.f) + log1pf(expf(-fabsf(dtr)));
    float du = dtv * u[i];
    float yv = 0.f;
    #pragma unroll
    for (int s = 0; s < DSt; ++s){
      h[s] = exp2f(dtv * a2[s]) * h[s] + du * row[24 + s];
      yv += h[s] * row[40 + s];
    }
    float sig = 1.f / (1.f + expf(-z[i]));
    xzu[(size_t)(l0+i)*1536] = (yv + u[i]*Dd) * (z[i] * sig);
  }
}

// -------------------------------------------------- final two LayerNorms
__global__ __launch_bounds__(256) void final_ln_kernel(const float* __restrict__ h,
                                                       const float* __restrict__ res,
                                                       const void* w1, const void* b1,
                                                       const void* w2, const void* b2,
                                                       float* __restrict__ x,
                                                       const int* __restrict__ dflag){
  const int f32 = *dflag;
  int wv = threadIdx.x >> 6, ln = threadIdx.x & 63;
  int tokid = blockIdx.x*4 + wv;
  const float* hr = h + (size_t)tokid*DM;
  const float* rr = res + (size_t)tokid*DM;
  float* xr = x + (size_t)tokid*DM;
  float v[6]; float s = 0.f;
  #pragma unroll
  for (int i = 0; i < 6; ++i){ int c = ln + 64*i; v[i] = hr[c] + rr[c]; s += v[i]; }
  #pragma unroll
  for (int o = 32; o > 0; o >>= 1) s += __shfl_xor(s, o);
  float mu = s * (1.f/DM); float q = 0.f;
  #pragma unroll
  for (int i = 0; i < 6; ++i){ float dd = v[i]-mu; q += dd*dd; }
  #pragma unroll
  for (int o = 32; o > 0; o >>= 1) q += __shfl_xor(q, o);
  float rstd = rsqrtf(q * (1.f/DM) + EPSf);
  float u[6]; float s2 = 0.f;
  #pragma unroll
  for (int i = 0; i < 6; ++i){ int c = ln + 64*i; u[i] = (v[i]-mu)*rstd*ld(w1,c,f32) + ld(b1,c,f32); s2 += u[i]; }
  #pragma unroll
  for (int o = 32; o > 0; o >>= 1) s2 += __shfl_xor(s2, o);
  float mu2 = s2 * (1.f/DM); float q2 = 0.f;
  #pragma unroll
  for (int i = 0; i < 6; ++i){ float dd = u[i]-mu2; q2 += dd*dd; }
  #pragma unroll
  for (int o = 32; o > 0; o >>= 1) q2 += __shfl_xor(q2, o);
  float rstd2 = rsqrtf(q2 * (1.f/DM) + EPSf);
  #pragma unroll
  for (int i = 0; i < 6; ++i){ int c = ln + 64*i; xr[c] = (u[i]-mu2)*rstd2*ld(w2,c,f32) + ld(b2,c,f32); }
}

// -------------------------------------------------- mean over L + MLP head
__global__ __launch_bounds__(384) void head_kernel(const float* __restrict__ x,
    const void* w1, const void* b1, const void* g1, const void* bb1,
    const void* w2, const void* b2, const void* g2, const void* bb2,
    const void* w3, const void* b3, void* __restrict__ out,
    const int* __restrict__ dflag){
  const int f32 = *dflag;
  int b = blockIdx.x; int t = threadIdx.x;
  __shared__ float feat[DM]; __shared__ float h1[256]; __shared__ float h2[256];
  float s = 0.f;
  for (int l = 0; l < Ln; ++l) s += x[((size_t)(b*Ln + l))*DM + t];
  feat[t] = s * (1.f/Ln);
  __syncthreads();
  if (t < 256){
    float a = ld(b1, t, f32);
    for (int j = 0; j < DM; ++j) a += ld(w1, (size_t)t*DM + j, f32) * feat[j];
    a = a * (ld(g1,t,f32) * BNS) + ld(bb1,t,f32);
    h1[t] = fmaxf(a, 0.f);
  }
  __syncthreads();
  if (t < 256){
    float a = ld(b2, t, f32);
    for (int j = 0; j < 256; ++j) a += ld(w2, (size_t)t*256 + j, f32) * h1[j];
    a = a * (ld(g2,t,f32) * BNS) + ld(bb2,t,f32);
    h2[t] = fmaxf(a, 0.f);
  }
  __syncthreads();
  if (t < CLSn){
    float a = ld(b3, t, f32);
    for (int j = 0; j < 256; ++j) a += ld(w3, (size_t)t*256 + j, f32) * h2[j];
    if (f32) ((float*)out)[b*CLSn + t] = a;
    else     ((bf16*)out)[b*CLSn + t] = __float2bfloat16(a);
  }
}

extern "C" void kernel_launch(void* const* d_in, const int* in_sizes, int n_in,
                              void* d_out, int out_size, void* d_ws, size_t ws_size,
                              hipStream_t stream) {
  if (n_in < 42) return;
  if (out_size < Bn*CLSn) return;
  constexpr size_t WS_FLOATS = 3919936; // hb + res + U + flag
  if (ws_size < WS_FLOATS * sizeof(float)) return;

  const void* pts       = d_in[0];
  const void* enc_w1    = d_in[1];  const void* enc_b1    = d_in[2];
  const void* enc_bn1_g = d_in[3];  const void* enc_bn1_b = d_in[4];
  const void* enc_w2    = d_in[5];  const void* enc_b2    = d_in[6];
  const void* enc_w3    = d_in[7];  const void* enc_b3    = d_in[8];
  const void* enc_bn2_g = d_in[9];  const void* enc_bn2_b = d_in[10];
  const void* enc_w4    = d_in[11]; const void* enc_b4    = d_in[12];
  const void* pos_w1    = d_in[13]; const void* pos_b1    = d_in[14];
  const void* pos_w2    = d_in[15]; const void* pos_b2    = d_in[16];
  const void* ln_w      = d_in[17]; const void* ln_b      = d_in[18];
  const void* in_proj_w = d_in[19];
  const void* conv_w    = d_in[20]; const void* conv_b    = d_in[21];
  const void* x_proj_w  = d_in[22];
  const void* dt_proj_w = d_in[23]; const void* dt_proj_b = d_in[24];
  const void* A_log     = d_in[25]; const void* D_param   = d_in[26];
  const void* out_proj_w= d_in[27];
  const void* normf_w   = d_in[28]; const void* normf_b   = d_in[29];
  const void* norm_w    = d_in[30]; const void* norm_b    = d_in[31];
  const void* head_w1   = d_in[32]; const void* head_b1   = d_in[33];
  const void* head_bn1_g= d_in[34]; const void* head_bn1_b= d_in[35];
  const void* head_w2   = d_in[36]; const void* head_b2   = d_in[37];
  const void* head_bn2_g= d_in[38]; const void* head_bn2_b= d_in[39];
  const void* head_w3   = d_in[40]; const void* head_b3   = d_in[41];

  float* ws = (float*)d_ws;
  float* hb   = ws;                   // 589,824 floats
  float* resb = ws + 589824;          // 589,824
  float* U    = ws + 1179648;         // 2,740,224
  int* dflag  = (int*)(ws + 3919872);
  // setup/encoder view of U
  float* center = U;
  float* nb     = U + 1536;
  float* tok    = U + 50688;
  int*   order  = (int*)(U + 247296);
  float* eb0    = U + 262144;
  float* eb1    = U + 1310720;
  // mamba view of U
  float* xz   = U;                      // 2,359,296
  float* xdb  = U + 2359296;            // 86,016
  bf16*  xb   = (bf16*)(U + 2445312);   // 589,824 bf16
  float* SBdt = U + 2445312 + 36864;    // aliases xb tail (xb dead when scanA runs)
  float* SBS  = hb;                     // aliases hb (dead between ln_res and out_proj)
  float* xf   = U;

  detect_kernel<<<1, 64, 0, stream>>>(pts, dflag);

  fps_kernel<<<Bn, 64, 0, stream>>>(pts, center, dflag);
  knn_kernel<<<Bn*Gn, 256, 0, stream>>>(pts, center, nb, dflag);

  for (int ch = 0; ch < 8; ++ch){
    const float* nb_c = nb + (size_t)ch*2048*3;
    float* tok_c = tok + (size_t)ch*64*DM;
    gemm_mfma<float,1><<<dim3(32,2), 256, 0, stream>>>(nb_c, 3, enc_w1, 0, enc_b1, 0,
        enc_bn1_g, enc_bn1_b, eb1, 128, 2048, 128, 3, dflag);
    gemm_mfma<float,0><<<dim3(32,4), 256, 0, stream>>>(eb1, 128, enc_w2, 0, enc_b2, 0,
        nullptr, nullptr, eb0 + 256, 512, 2048, 256, 128, dflag);
    maxk_fg<<<64, 256, 0, stream>>>(eb0);
    gemm_mfma<float,1><<<dim3(32,8), 256, 0, stream>>>(eb0, 512, enc_w3, 0, enc_b3, 0,
        enc_bn2_g, enc_bn2_b, eb1, 512, 2048, 512, 512, dflag);
    gemm_mfma<float,0><<<dim3(32,6), 256, 0, stream>>>(eb1, 512, enc_w4, 0, enc_b4, 0,
        nullptr, nullptr, eb0, 384, 2048, 384, 512, dflag);
    maxk_tok<<<64, 384, 0, stream>>>(eb0, tok_c);
  }

  pos_kernel<<<Bn*Gn, 128, 0, stream>>>(center, pos_w1, pos_b1, pos_w2, pos_b2, tok, dflag);
  sort_kernel<<<Bn*3, 128, 0, stream>>>(center, order);
  build_h<<<(Bn*Ln*DM + 255)/256, 256, 0, stream>>>(tok, order, hb, resb);

  for (int l = 0; l < DEPTH; ++l){
    size_t o_ln  = (size_t)l*DM;
    size_t o_ip  = (size_t)l*1536*DM;
    size_t o_cw  = (size_t)l*DI*4;
    size_t o_cb  = (size_t)l*DI;
    size_t o_xp  = (size_t)l*56*DI;
    size_t o_dpw = (size_t)l*DI*DTR;
    size_t o_dpb = (size_t)l*DI;
    size_t o_Al  = (size_t)l*DI*DSt;
    size_t o_Dp  = (size_t)l*DI;
    size_t o_op  = (size_t)l*DM*DI;

    ln_res_kernel<<<Bn*Ln/4, 256, 0, stream>>>(hb, resb, xb, ln_w, o_ln, ln_b, dflag);
    gemm_mfma<bf16,0><<<dim3(24,24), 256, 0, stream>>>(xb, DM, in_proj_w, o_ip,
        nullptr, 0, nullptr, nullptr, xz, 1536, Bn*Ln, 1536, DM, dflag);
    conv_kernel<<<Bn*DI/256, 256, 0, stream>>>(xz, conv_w, o_cw, conv_b, o_cb, dflag);
    gemm_mfma<float,0><<<dim3(24,1), 256, 0, stream>>>(xz, 1536, x_proj_w, o_xp,
        nullptr, 0, nullptr, nullptr, xdb, 56, Bn*Ln, 56, DI, dflag);
    scanA_kernel<<<Bn*3*NCH, 256, 0, stream>>>(xz, xdb, dt_proj_w, o_dpw, dt_proj_b, o_dpb,
        A_log, o_Al, SBS, SBdt, dflag);
    scanC_kernel<<<12, 256, 0, stream>>>(SBS, SBdt, A_log, o_Al, dflag);
    scanB_kernel<<<Bn*3*NCH, 256, 0, stream>>>(xz, xdb, dt_proj_w, o_dpw, dt_proj_b, o_dpb,
        A_log, o_Al, D_param, o_Dp, SBS, dflag);
    gemm_mfma<float,0><<<dim3(24,6), 256, 0, stream>>>(xz, 1536, out_proj_w, o_op,
        nullptr, 0, nullptr, nullptr, hb, DM, Bn*Ln, DM, DI, dflag);
  }

  final_ln_kernel<<<Bn*Ln/4, 256, 0, stream>>>(hb, resb, normf_w, normf_b, norm_w, norm_b, xf, dflag);
  head_kernel<<<Bn, 384, 0, stream>>>(xf, head_w1, head_b1, head_bn1_g, head_bn1_b,
                                      head_w2, head_b2, head_bn2_g, head_bn2_b,
                                      head_w3, head_b3, d_out, dflag);
}

// Round 7
// 2511.871 us; speedup vs baseline: 2.6617x; 2.6617x over previous
//
#include <hip/hip_runtime.h>
#include <hip/hip_bf16.h>

using bf16 = __hip_bfloat16;
using short8  = __attribute__((ext_vector_type(8))) short;
using floatx4 = __attribute__((ext_vector_type(4))) float;

constexpr int Bn = 4, Np = 1024, Gn = 128, Kn = 32;
constexpr int DM = 384, DEPTH = 12, CLSn = 40;
constexpr int DI = 768, DSt = 16, DTR = 24;
constexpr int Ln = 384;
constexpr int NCH = 12, CHS = 32;      // scan: 12 chunks x 32 steps
constexpr int NLC = 24;                // conv: 24 chunks x 16 steps
constexpr float EPSf = 1e-5f;
constexpr float BNS = 0.99999500003749968752f; // 1/sqrt(1+1e-5)
constexpr float LOG2E = 1.4426950408889634f;

static __device__ __forceinline__ short f2bf(float f){
  bf16 h = __float2bfloat16(f);
  return *reinterpret_cast<short*>(&h);
}
static __device__ __forceinline__ float fsig(float x){ return 1.f/(1.f + __expf(-x)); }
static __device__ __forceinline__ float fsoftplus(float x){
  return fmaxf(x, 0.f) + __logf(1.f + __expf(-fabsf(x)));
}

// ---------------------------------------------------------------- FPS (single wave)
__global__ __launch_bounds__(64) void fps_kernel(const float* __restrict__ pts,
                                                 float* __restrict__ center){
  int b = blockIdx.x;
  __shared__ float xs[1024], ys[1024], zs[1024];
  int t = threadIdx.x;
  const float* p = pts + (size_t)b * Np * 3;
  float dmin[16];
  #pragma unroll
  for (int i = 0; i < 16; ++i){
    int n = t + 64*i;
    xs[n] = p[n*3+0]; ys[n] = p[n*3+1]; zs[n] = p[n*3+2];
    dmin[i] = 1e10f;
  }
  if (t == 0){
    center[(size_t)(b*Gn)*3+0] = xs[0];
    center[(size_t)(b*Gn)*3+1] = ys[0];
    center[(size_t)(b*Gn)*3+2] = zs[0];
  }
  int last = 0;
  for (int it = 1; it < Gn; ++it){
    float px = xs[last], py = ys[last], pz = zs[last];
    float v = -1.f; int idx = 0;
    #pragma unroll
    for (int i = 0; i < 16; ++i){
      int n = t + 64*i;
      float dx = __fsub_rn(xs[n], px);
      float dy = __fsub_rn(ys[n], py);
      float dz = __fsub_rn(zs[n], pz);
      float d  = __fadd_rn(__fadd_rn(__fmul_rn(dx,dx), __fmul_rn(dy,dy)), __fmul_rn(dz,dz));
      float dm = fminf(dmin[i], d); dmin[i] = dm;
      if (dm > v){ v = dm; idx = n; }
    }
    #pragma unroll
    for (int o = 32; o > 0; o >>= 1){
      float v2 = __shfl_down(v, o); int i2 = __shfl_down(idx, o);
      if (v2 > v || (v2 == v && i2 < idx)){ v = v2; idx = i2; }
    }
    idx = __shfl(idx, 0);
    idx = min(max(idx, 0), Np-1);
    if (t == 0){
      center[(size_t)(b*Gn+it)*3+0] = xs[idx];
      center[(size_t)(b*Gn+it)*3+1] = ys[idx];
      center[(size_t)(b*Gn+it)*3+2] = zs[idx];
    }
    last = idx;
  }
}

// ---------------------------------------------------------------- KNN
__global__ __launch_bounds__(256) void knn_kernel(const float* __restrict__ pts,
                                                  const float* __restrict__ center,
                                                  float* __restrict__ nb){
  int gid = blockIdx.x; int b = gid >> 7;
  __shared__ float d2[1024];
  __shared__ float rv[4]; __shared__ int ri[4];
  int t = threadIdx.x;
  float cx = center[(size_t)gid*3+0], cy = center[(size_t)gid*3+1], cz = center[(size_t)gid*3+2];
  const float* p = pts + (size_t)b * Np * 3;
  for (int n = t; n < Np; n += 256){
    float dx = __fsub_rn(cx, p[n*3+0]);
    float dy = __fsub_rn(cy, p[n*3+1]);
    float dz = __fsub_rn(cz, p[n*3+2]);
    d2[n] = __fadd_rn(__fadd_rn(__fmul_rn(dx,dx), __fmul_rn(dy,dy)), __fmul_rn(dz,dz));
  }
  __syncthreads();
  for (int kk = 0; kk < Kn; ++kk){
    float v = 3e38f; int idx = 0;
    for (int n = t; n < Np; n += 256){
      float d = d2[n];
      if (d < v || (d == v && n < idx)){ v = d; idx = n; }
    }
    #pragma unroll
    for (int o = 32; o > 0; o >>= 1){
      float v2 = __shfl_down(v, o); int i2 = __shfl_down(idx, o);
      if (v2 < v || (v2 == v && i2 < idx)){ v = v2; idx = i2; }
    }
    if ((t & 63) == 0){ rv[t>>6] = v; ri[t>>6] = idx; }
    __syncthreads();
    if (t == 0){
      float bv = rv[0]; int bi = ri[0];
      for (int w = 1; w < 4; ++w){
        if (rv[w] < bv || (rv[w] == bv && ri[w] < bi)){ bv = rv[w]; bi = ri[w]; }
      }
      bi = min(max(bi, 0), Np-1);
      nb[((size_t)gid*Kn+kk)*3+0] = __fsub_rn(p[bi*3+0], cx);
      nb[((size_t)gid*Kn+kk)*3+1] = __fsub_rn(p[bi*3+1], cy);
      nb[((size_t)gid*Kn+kk)*3+2] = __fsub_rn(p[bi*3+2], cz);
      d2[bi] = 3e38f;
    }
    __syncthreads();
  }
}

// ---------------------------------------------------------------- MFMA GEMM
// C[M,N] = act(A[M,K](lda) @ W[N,K]^T + bias). bf16 MFMA, fp32 accumulate.
// GATE: A element = y[m,k] * silu(z[m,k]) with z at A col offset +768.
template<typename AT, int ACT, int GATE>
__global__ __launch_bounds__(256) void gemm_mfma(const AT* __restrict__ A, int lda,
                                                 const float* __restrict__ W,
                                                 const float* __restrict__ bias,
                                                 const float* __restrict__ g,
                                                 const float* __restrict__ bb,
                                                 float* __restrict__ C, int ldc,
                                                 int M, int N, int K){
  __shared__ __align__(16) short As[64*40];
  __shared__ __align__(16) short Ws[64*40];
  int bm = blockIdx.x * 64, bn = blockIdx.y * 64;
  int t = threadIdx.x;
  int row = t >> 2;            // 0..63 staging row
  int kseg = (t & 3) * 8;      // 0,8,16,24
  int w = t >> 6, lane = t & 63, m16 = lane & 15, q = lane >> 4;
  bool kvec = ((K & 3) == 0) && ((lda & 3) == 0 || sizeof(AT) == 2);
  floatx4 acc[4] = {};
  for (int k0 = 0; k0 < K; k0 += 32){
    // ---- A staging
    if constexpr (GATE){
      const float* Ar = (const float*)A + (size_t)(bm + row)*lda + k0 + kseg;
      float4 y0 = *(const float4*)Ar;
      float4 y1 = *(const float4*)(Ar + 4);
      float4 z0 = *(const float4*)(Ar + 768);
      float4 z1 = *(const float4*)(Ar + 772);
      short* dst = &As[row*40 + kseg];
      dst[0] = f2bf(y0.x * (z0.x * fsig(z0.x)));
      dst[1] = f2bf(y0.y * (z0.y * fsig(z0.y)));
      dst[2] = f2bf(y0.z * (z0.z * fsig(z0.z)));
      dst[3] = f2bf(y0.w * (z0.w * fsig(z0.w)));
      dst[4] = f2bf(y1.x * (z1.x * fsig(z1.x)));
      dst[5] = f2bf(y1.y * (z1.y * fsig(z1.y)));
      dst[6] = f2bf(y1.z * (z1.z * fsig(z1.z)));
      dst[7] = f2bf(y1.w * (z1.w * fsig(z1.w)));
    } else if constexpr (sizeof(AT) == 2){
      *(short8*)&As[row*40 + kseg] =
          *(const short8*)((const short*)A + (size_t)(bm + row)*lda + k0 + kseg);
    } else {
      const float* Ar = (const float*)A + (size_t)(bm + row)*lda;
      short* dst = &As[row*40 + kseg];
      if (kvec && (k0 + kseg + 8 <= K)){
        float4 a0 = *(const float4*)(Ar + k0 + kseg);
        float4 a1 = *(const float4*)(Ar + k0 + kseg + 4);
        dst[0]=f2bf(a0.x); dst[1]=f2bf(a0.y); dst[2]=f2bf(a0.z); dst[3]=f2bf(a0.w);
        dst[4]=f2bf(a1.x); dst[5]=f2bf(a1.y); dst[6]=f2bf(a1.z); dst[7]=f2bf(a1.w);
      } else {
        #pragma unroll
        for (int j = 0; j < 8; ++j){
          int k = k0 + kseg + j;
          dst[j] = (k < K) ? f2bf(Ar[k]) : (short)0;
        }
      }
    }
    // ---- W staging
    {
      int n = bn + row;
      short* dst = &Ws[row*40 + kseg];
      if (n < N && ((K & 3) == 0) && (k0 + kseg + 8 <= K)){
        const float* Wr = W + (size_t)n*K + k0 + kseg;
        float4 w0 = *(const float4*)Wr;
        float4 w1 = *(const float4*)(Wr + 4);
        dst[0]=f2bf(w0.x); dst[1]=f2bf(w0.y); dst[2]=f2bf(w0.z); dst[3]=f2bf(w0.w);
        dst[4]=f2bf(w1.x); dst[5]=f2bf(w1.y); dst[6]=f2bf(w1.z); dst[7]=f2bf(w1.w);
      } else {
        #pragma unroll
        for (int j = 0; j < 8; ++j){
          int k = k0 + kseg + j;
          dst[j] = (n < N && k < K) ? f2bf(W[(size_t)n*K + k]) : (short)0;
        }
      }
    }
    __syncthreads();
    short8 af = *(const short8*)&As[(w*16 + m16)*40 + q*8];
    #pragma unroll
    for (int j = 0; j < 4; ++j){
      short8 bfr = *(const short8*)&Ws[(j*16 + m16)*40 + q*8];
      acc[j] = __builtin_amdgcn_mfma_f32_16x16x32_bf16(af, bfr, acc[j], 0, 0, 0);
    }
    __syncthreads();
  }
  #pragma unroll
  for (int j = 0; j < 4; ++j){
    int n = bn + j*16 + m16;
    if (n < N){
      float bv = bias ? bias[n] : 0.f;
      float gv = 0.f, bbv = 0.f;
      if (ACT == 1){ gv = g[n] * BNS; bbv = bb[n]; }
      #pragma unroll
      for (int r = 0; r < 4; ++r){
        int m = bm + w*16 + q*4 + r;
        float v = acc[j][r] + bv;
        if (ACT == 1){ v = v * gv + bbv; v = fmaxf(v, 0.f); }
        C[(size_t)m*ldc + n] = v;
      }
    }
  }
}

// -------------------------------------------------- encoder max-pools
__global__ __launch_bounds__(256) void maxk_fg(float* __restrict__ f3in){
  int gg = blockIdx.x; int c = threadIdx.x;
  float m = -3e38f;
  for (int k = 0; k < Kn; ++k) m = fmaxf(m, f3in[((size_t)gg*Kn + k)*512 + 256 + c]);
  for (int k = 0; k < Kn; ++k) f3in[((size_t)gg*Kn + k)*512 + c] = m;
}

__global__ __launch_bounds__(384) void maxk_tok(const float* __restrict__ f4, float* __restrict__ tok){
  int gg = blockIdx.x; int c = threadIdx.x;
  float m = -3e38f;
  for (int k = 0; k < Kn; ++k) m = fmaxf(m, f4[((size_t)gg*Kn + k)*DM + c]);
  tok[(size_t)gg*DM + c] = m;
}

// -------------------------------------------------- pos embedding (adds into tok)
__global__ __launch_bounds__(128) void pos_kernel(const float* __restrict__ center,
                                                  const float* __restrict__ w1, const float* __restrict__ b1,
                                                  const float* __restrict__ w2, const float* __restrict__ b2,
                                                  float* __restrict__ tok){
  int gid = blockIdx.x;
  __shared__ float h1[128]; __shared__ float c3[3];
  int t = threadIdx.x;
  if (t < 3) c3[t] = center[(size_t)gid*3 + t];
  __syncthreads();
  float a = w1[t*3+0]*c3[0] + w1[t*3+1]*c3[1] + w1[t*3+2]*c3[2] + b1[t];
  h1[t] = 0.5f * a * (1.f + erff(a * 0.70710678118654752440f));
  __syncthreads();
  for (int c = t; c < DM; c += 128){
    float s = b2[c];
    for (int j = 0; j < 128; ++j) s += w2[(size_t)c*128 + j] * h1[j];
    tok[(size_t)gid*DM + c] += s;
  }
}

// -------------------------------------------------- stable argsort (rank count)
__global__ __launch_bounds__(128) void sort_kernel(const float* __restrict__ center,
                                                   int* __restrict__ order){
  int bax = blockIdx.x; int b = bax / 3, ax = bax % 3;
  __shared__ float key[128];
  int t = threadIdx.x;
  key[t] = center[(size_t)(b*Gn + t)*3 + ax];
  __syncthreads();
  float kt = key[t]; int r = 0;
  for (int j = 0; j < Gn; ++j){
    float kj = key[j];
    r += (kj < kt || (kj == kt && j < t)) ? 1 : 0;
  }
  r = min(max(r, 0), Gn-1);
  order[b*Ln + ax*Gn + r] = t;
}

// -------------------------------------------------- token gather + res init
__global__ __launch_bounds__(256) void build_h(const float* __restrict__ tok,
                        const int* __restrict__ order,
                        float* __restrict__ h, float* __restrict__ res){
  int i = blockIdx.x * blockDim.x + threadIdx.x;
  if (i >= Bn*Ln*DM) return;
  int c = i % DM; int l = (i / DM) % Ln; int b = i / (DM*Ln);
  int src = order[b*Ln + l];
  src = min(max(src, 0), Gn-1);
  h[i] = tok[((size_t)(b*Gn + src))*DM + c];
  res[i] = 0.f;
}

// -------------------------------------------------- res += h; x = LN(res)*w+b (bf16 out)
__global__ __launch_bounds__(256) void ln_res_kernel(const float* __restrict__ h,
                                                     float* __restrict__ res,
                                                     bf16* __restrict__ x,
                                                     const float* __restrict__ w,
                                                     const float* __restrict__ bias){
  int wv = threadIdx.x >> 6, ln = threadIdx.x & 63;
  int tokid = blockIdx.x*4 + wv;
  const float* hr = h + (size_t)tokid*DM;
  float* rr = res + (size_t)tokid*DM;
  bf16* xr = x + (size_t)tokid*DM;
  float v[6]; float s = 0.f;
  #pragma unroll
  for (int i = 0; i < 6; ++i){ int c = ln + 64*i; float t = hr[c] + rr[c]; rr[c] = t; v[i] = t; s += t; }
  #pragma unroll
  for (int o = 32; o > 0; o >>= 1) s += __shfl_xor(s, o);
  float mu = s * (1.f/DM);
  float q = 0.f;
  #pragma unroll
  for (int i = 0; i < 6; ++i){ float d = v[i] - mu; q += d*d; }
  #pragma unroll
  for (int o = 32; o > 0; o >>= 1) q += __shfl_xor(q, o);
  float rstd = rsqrtf(q * (1.f/DM) + EPSf);
  #pragma unroll
  for (int i = 0; i < 6; ++i){ int c = ln + 64*i;
    xr[c] = __float2bfloat16((v[i]-mu)*rstd*w[c] + bias[c]); }
}

// -------------------------------------------------- conv pass 1: save chunk boundaries
__global__ __launch_bounds__(256) void conv_save(const float* __restrict__ xz,
                                                 float* __restrict__ bnd){
  int blk = blockIdx.x;                     // (b*3+dch)*NLC + lc
  int lc = blk % NLC; int bd = blk / NLC; int dch = bd % 3; int b = bd / 3;
  int t = threadIdx.x; int d = dch*256 + t;
  int l0 = lc*16;
  #pragma unroll
  for (int j = 0; j < 3; ++j){
    int l = l0 - 3 + j;
    float v = (l >= 0) ? xz[((size_t)(b*Ln + l))*1536 + d] : 0.f;
    bnd[(((size_t)blk)*3 + j)*256 + t] = v;
  }
}

// -------------------------------------------------- conv pass 2: parallel FIR + silu (in place)
__global__ __launch_bounds__(256) void conv_apply(float* __restrict__ xz,
                                                  const float* __restrict__ bnd,
                                                  const float* __restrict__ cw,
                                                  const float* __restrict__ cb){
  int blk = blockIdx.x;
  int lc = blk % NLC; int bd = blk / NLC; int dch = bd % 3; int b = bd / 3;
  int t = threadIdx.x; int d = dch*256 + t;
  int l0 = lc*16;
  float w0 = cw[d*4+0], w1 = cw[d*4+1], w2 = cw[d*4+2], w3 = cw[d*4+3];
  float bias = cb[d];
  float u0 = bnd[(((size_t)blk)*3 + 0)*256 + t];
  float u1 = bnd[(((size_t)blk)*3 + 1)*256 + t];
  float u2 = bnd[(((size_t)blk)*3 + 2)*256 + t];
  float* p = xz + ((size_t)(b*Ln + l0))*1536 + d;
  float r[16];
  #pragma unroll
  for (int i = 0; i < 16; ++i) r[i] = p[(size_t)i*1536];
  #pragma unroll
  for (int i = 0; i < 16; ++i){
    float v = u0*w0 + u1*w1 + u2*w2 + r[i]*w3 + bias;
    p[(size_t)i*1536] = v * fsig(v);
    u0 = u1; u1 = u2; u2 = r[i];
  }
}

// -------------------------------------------------- chunked selective scan
// Phase A: per (b,dch,chunk) block, local scan from h=0 -> S[16], sum dt.
// u staged through LDS (no per-thread indexable arrays -> no scratch).
__global__ __launch_bounds__(256) void scanA_kernel(const float* __restrict__ xz,
                                                    const float* __restrict__ xdb,
                                                    const float* __restrict__ dpw,
                                                    const float* __restrict__ dpb,
                                                    const float* __restrict__ A_log,
                                                    float* __restrict__ SB_S,
                                                    float* __restrict__ SB_dt){
  __shared__ float sRow[CHS*56];   // 7 KB
  __shared__ float sU[CHS*256];    // 32 KB
  int blk = blockIdx.x;
  int c = blk % NCH; int bd = blk / NCH; int dch = bd % 3; int b = bd / 3;
  int t = threadIdx.x; int d = dch*256 + t;
  int l0 = c*CHS;
  for (int i = t; i < CHS*56; i += 256) sRow[i] = xdb[((size_t)(b*Ln + l0))*56 + i];
  const float* xzu = xz + ((size_t)(b*Ln + l0))*1536 + dch*256;
  #pragma unroll
  for (int i = 0; i < CHS; ++i) sU[i*256 + t] = xzu[(size_t)i*1536 + t];
  float w[DTR];
  const float* wp = dpw + (size_t)d*DTR;
  #pragma unroll
  for (int j = 0; j < DTR; ++j) w[j] = wp[j];
  float a2[DSt], h[DSt];
  const float* ap = A_log + (size_t)d*DSt;
  #pragma unroll
  for (int s = 0; s < DSt; ++s){ a2[s] = -__expf(ap[s]) * LOG2E; h[s] = 0.f; }
  float dbias = dpb[d];
  float sumdt = 0.f;
  __syncthreads();
  for (int i = 0; i < CHS; ++i){
    int ro = i*56;
    float dtr = dbias;
    #pragma unroll
    for (int j = 0; j < DTR; ++j) dtr += w[j] * sRow[ro + j];
    float dtv = fsoftplus(dtr);
    sumdt += dtv;
    float du = dtv * sU[i*256 + t];
    #pragma unroll
    for (int s = 0; s < DSt; ++s)
      h[s] = exp2f(dtv * a2[s]) * h[s] + du * sRow[ro + 24 + s];
  }
  size_t sb = ((size_t)blk*256 + t)*16;
  #pragma unroll
  for (int s = 0; s < DSt; ++s) SB_S[sb + s] = h[s];
  SB_dt[(size_t)blk*256 + t] = sumdt;
}

// Combine: sequential prefix over chunks; SB_S[c] := h_in(c)
__global__ __launch_bounds__(256) void scanC_kernel(float* __restrict__ SB_S,
                                                    const float* __restrict__ SB_dt,
                                                    const float* __restrict__ A_log){
  int id = blockIdx.x*256 + threadIdx.x;   // 0..3071
  int t = id & 255; int bd = id >> 8;
  int d = (bd % 3)*256 + t;
  float a2[DSt];
  #pragma unroll
  for (int s = 0; s < DSt; ++s) a2[s] = -__expf(A_log[(size_t)d*DSt + s]) * LOG2E;
  float h[DSt];
  #pragma unroll
  for (int s = 0; s < DSt; ++s) h[s] = 0.f;
  for (int c = 0; c < NCH; ++c){
    size_t base = (((size_t)bd*NCH + c)*256 + t)*16;
    float sd = SB_dt[((size_t)bd*NCH + c)*256 + t];
    #pragma unroll
    for (int s = 0; s < DSt; ++s){
      float S = SB_S[base + s];
      SB_S[base + s] = h[s];
      h[s] = exp2f(sd * a2[s]) * h[s] + S;
    }
  }
}

// Phase B: re-run chunk from correct h_in, write UNGATED y (gate in out_proj)
__global__ __launch_bounds__(256) void scanB_kernel(float* __restrict__ xz,
                                                    const float* __restrict__ xdb,
                                                    const float* __restrict__ dpw,
                                                    const float* __restrict__ dpb,
                                                    const float* __restrict__ A_log,
                                                    const float* __restrict__ Dp,
                                                    const float* __restrict__ SB_S){
  __shared__ float sRow[CHS*56];
  __shared__ float sU[CHS*256];
  int blk = blockIdx.x;
  int c = blk % NCH; int bd = blk / NCH; int dch = bd % 3; int b = bd / 3;
  int t = threadIdx.x; int d = dch*256 + t;
  int l0 = c*CHS;
  for (int i = t; i < CHS*56; i += 256) sRow[i] = xdb[((size_t)(b*Ln + l0))*56 + i];
  float* xzu = xz + ((size_t)(b*Ln + l0))*1536 + dch*256;
  #pragma unroll
  for (int i = 0; i < CHS; ++i) sU[i*256 + t] = xzu[(size_t)i*1536 + t];
  float w[DTR];
  const float* wp = dpw + (size_t)d*DTR;
  #pragma unroll
  for (int j = 0; j < DTR; ++j) w[j] = wp[j];
  float a2[DSt], h[DSt];
  const float* ap = A_log + (size_t)d*DSt;
  #pragma unroll
  for (int s = 0; s < DSt; ++s) a2[s] = -__expf(ap[s]) * LOG2E;
  size_t sb = ((size_t)blk*256 + t)*16;
  #pragma unroll
  for (int s = 0; s < DSt; ++s) h[s] = SB_S[sb + s];
  float dbias = dpb[d];
  float Dd = Dp[d];
  __syncthreads();
  for (int i = 0; i < CHS; ++i){
    int ro = i*56;
    float dtr = dbias;
    #pragma unroll
    for (int j = 0; j < DTR; ++j) dtr += w[j] * sRow[ro + j];
    float dtv = fsoftplus(dtr);
    float u = sU[i*256 + t];
    float du = dtv * u;
    float yv = 0.f;
    #pragma unroll
    for (int s = 0; s < DSt; ++s){
      h[s] = exp2f(dtv * a2[s]) * h[s] + du * sRow[ro + 24 + s];
      yv += h[s] * sRow[ro + 40 + s];
    }
    xzu[(size_t)i*1536 + t] = yv + u*Dd;   // ungated; gate applied in out_proj staging
  }
}

// -------------------------------------------------- final two LayerNorms
__global__ __launch_bounds__(256) void final_ln_kernel(const float* __restrict__ h,
                                                       const float* __restrict__ res,
                                                       const float* w1, const float* b1,
                                                       const float* w2, const float* b2,
                                                       float* __restrict__ x){
  int wv = threadIdx.x >> 6, ln = threadIdx.x & 63;
  int tokid = blockIdx.x*4 + wv;
  const float* hr = h + (size_t)tokid*DM;
  const float* rr = res + (size_t)tokid*DM;
  float* xr = x + (size_t)tokid*DM;
  float v[6]; float s = 0.f;
  #pragma unroll
  for (int i = 0; i < 6; ++i){ int c = ln + 64*i; v[i] = hr[c] + rr[c]; s += v[i]; }
  #pragma unroll
  for (int o = 32; o > 0; o >>= 1) s += __shfl_xor(s, o);
  float mu = s * (1.f/DM); float q = 0.f;
  #pragma unroll
  for (int i = 0; i < 6; ++i){ float dd = v[i]-mu; q += dd*dd; }
  #pragma unroll
  for (int o = 32; o > 0; o >>= 1) q += __shfl_xor(q, o);
  float rstd = rsqrtf(q * (1.f/DM) + EPSf);
  float u[6]; float s2 = 0.f;
  #pragma unroll
  for (int i = 0; i < 6; ++i){ int c = ln + 64*i; u[i] = (v[i]-mu)*rstd*w1[c] + b1[c]; s2 += u[i]; }
  #pragma unroll
  for (int o = 32; o > 0; o >>= 1) s2 += __shfl_xor(s2, o);
  float mu2 = s2 * (1.f/DM); float q2 = 0.f;
  #pragma unroll
  for (int i = 0; i < 6; ++i){ float dd = u[i]-mu2; q2 += dd*dd; }
  #pragma unroll
  for (int o = 32; o > 0; o >>= 1) q2 += __shfl_xor(q2, o);
  float rstd2 = rsqrtf(q2 * (1.f/DM) + EPSf);
  #pragma unroll
  for (int i = 0; i < 6; ++i){ int c = ln + 64*i; xr[c] = (u[i]-mu2)*rstd2*w2[c] + b2[c]; }
}

// -------------------------------------------------- mean over L + MLP head
__global__ __launch_bounds__(384) void head_kernel(const float* __restrict__ x,
    const float* w1, const float* b1, const float* g1, const float* bb1,
    const float* w2, const float* b2, const float* g2, const float* bb2,
    const float* w3, const float* b3, float* __restrict__ out){
  int b = blockIdx.x; int t = threadIdx.x;
  __shared__ float feat[DM]; __shared__ float h1[256]; __shared__ float h2[256];
  float s = 0.f;
  for (int l = 0; l < Ln; ++l) s += x[((size_t)(b*Ln + l))*DM + t];
  feat[t] = s * (1.f/Ln);
  __syncthreads();
  if (t < 256){
    float a = b1[t];
    for (int j = 0; j < DM; ++j) a += w1[(size_t)t*DM + j] * feat[j];
    a = a * (g1[t] * BNS) + bb1[t];
    h1[t] = fmaxf(a, 0.f);
  }
  __syncthreads();
  if (t < 256){
    float a = b2[t];
    for (int j = 0; j < 256; ++j) a += w2[(size_t)t*256 + j] * h1[j];
    a = a * (g2[t] * BNS) + bb2[t];
    h2[t] = fmaxf(a, 0.f);
  }
  __syncthreads();
  if (t < CLSn){
    float a = b3[t];
    for (int j = 0; j < 256; ++j) a += w3[(size_t)t*256 + j] * h2[j];
    out[b*CLSn + t] = a;
  }
}

extern "C" void kernel_launch(void* const* d_in, const int* in_sizes, int n_in,
                              void* d_out, int out_size, void* d_ws, size_t ws_size,
                              hipStream_t stream) {
  if (n_in < 42) return;
  if (out_size < Bn*CLSn) return;
  constexpr size_t WS_FLOATS = 3919936;
  if (ws_size < WS_FLOATS * sizeof(float)) return;

  const float* pts       = (const float*)d_in[0];
  const float* enc_w1    = (const float*)d_in[1];  const float* enc_b1    = (const float*)d_in[2];
  const float* enc_bn1_g = (const float*)d_in[3];  const float* enc_bn1_b = (const float*)d_in[4];
  const float* enc_w2    = (const float*)d_in[5];  const float* enc_b2    = (const float*)d_in[6];
  const float* enc_w3    = (const float*)d_in[7];  const float* enc_b3    = (const float*)d_in[8];
  const float* enc_bn2_g = (const float*)d_in[9];  const float* enc_bn2_b = (const float*)d_in[10];
  const float* enc_w4    = (const float*)d_in[11]; const float* enc_b4    = (const float*)d_in[12];
  const float* pos_w1    = (const float*)d_in[13]; const float* pos_b1    = (const float*)d_in[14];
  const float* pos_w2    = (const float*)d_in[15]; const float* pos_b2    = (const float*)d_in[16];
  const float* ln_w      = (const float*)d_in[17]; const float* ln_b      = (const float*)d_in[18];
  const float* in_proj_w = (const float*)d_in[19];
  const float* conv_w    = (const float*)d_in[20]; const float* conv_b    = (const float*)d_in[21];
  const float* x_proj_w  = (const float*)d_in[22];
  const float* dt_proj_w = (const float*)d_in[23]; const float* dt_proj_b = (const float*)d_in[24];
  const float* A_log     = (const float*)d_in[25]; const float* D_param   = (const float*)d_in[26];
  const float* out_proj_w= (const float*)d_in[27];
  const float* normf_w   = (const float*)d_in[28]; const float* normf_b   = (const float*)d_in[29];
  const float* norm_w    = (const float*)d_in[30]; const float* norm_b    = (const float*)d_in[31];
  const float* head_w1   = (const float*)d_in[32]; const float* head_b1   = (const float*)d_in[33];
  const float* head_bn1_g= (const float*)d_in[34]; const float* head_bn1_b= (const float*)d_in[35];
  const float* head_w2   = (const float*)d_in[36]; const float* head_b2   = (const float*)d_in[37];
  const float* head_bn2_g= (const float*)d_in[38]; const float* head_bn2_b= (const float*)d_in[39];
  const float* head_w3   = (const float*)d_in[40]; const float* head_b3   = (const float*)d_in[41];

  float* ws = (float*)d_ws;
  float* hb   = ws;                   // 589,824 floats
  float* resb = ws + 589824;          // 589,824
  float* U    = ws + 1179648;         // 2,740,224
  // setup/encoder view of U
  float* center = U;
  float* nb     = U + 1536;
  float* tok    = U + 50688;
  int*   order  = (int*)(U + 247296);
  float* eb0    = U + 262144;
  float* eb1    = U + 1310720;
  // mamba view of U
  float* xz   = U;                      // 2,359,296 (1536 x 1536)
  float* xdb  = U + 2359296;            // 86,016
  bf16*  xb   = (bf16*)(U + 2445312);   // 589,824 bf16 in 294,912 float slots
  float* SBdt = U + 2445312;            // 36,864 (xb dead when scanA runs)
  float* BND  = U + 2482176;            // 221,184 (ends 2,703,360 < 2,740,224)
  float* SBS  = hb;                     // 589,824 (hb dead between ln_res and out_proj)
  float* xf   = U;

  fps_kernel<<<Bn, 64, 0, stream>>>(pts, center);
  knn_kernel<<<Bn*Gn, 256, 0, stream>>>(pts, center, nb);

  for (int ch = 0; ch < 8; ++ch){
    const float* nb_c = nb + (size_t)ch*2048*3;
    float* tok_c = tok + (size_t)ch*64*DM;
    gemm_mfma<float,1,0><<<dim3(32,2), 256, 0, stream>>>(nb_c, 3, enc_w1, enc_b1,
        enc_bn1_g, enc_bn1_b, eb1, 128, 2048, 128, 3);
    gemm_mfma<float,0,0><<<dim3(32,4), 256, 0, stream>>>(eb1, 128, enc_w2, enc_b2,
        nullptr, nullptr, eb0 + 256, 512, 2048, 256, 128);
    maxk_fg<<<64, 256, 0, stream>>>(eb0);
    gemm_mfma<float,1,0><<<dim3(32,8), 256, 0, stream>>>(eb0, 512, enc_w3, enc_b3,
        enc_bn2_g, enc_bn2_b, eb1, 512, 2048, 512, 512);
    gemm_mfma<float,0,0><<<dim3(32,6), 256, 0, stream>>>(eb1, 512, enc_w4, enc_b4,
        nullptr, nullptr, eb0, 384, 2048, 384, 512);
    maxk_tok<<<64, 384, 0, stream>>>(eb0, tok_c);
  }

  pos_kernel<<<Bn*Gn, 128, 0, stream>>>(center, pos_w1, pos_b1, pos_w2, pos_b2, tok);
  sort_kernel<<<Bn*3, 128, 0, stream>>>(center, order);
  build_h<<<(Bn*Ln*DM + 255)/256, 256, 0, stream>>>(tok, order, hb, resb);

  for (int l = 0; l < DEPTH; ++l){
    const float* lnw  = ln_w      + (size_t)l*DM;
    const float* lnb  = ln_b      + (size_t)l*DM;
    const float* ipw  = in_proj_w + (size_t)l*1536*DM;
    const float* cw   = conv_w    + (size_t)l*DI*4;
    const float* cb   = conv_b    + (size_t)l*DI;
    const float* xpw  = x_proj_w  + (size_t)l*56*DI;
    const float* dpw  = dt_proj_w + (size_t)l*DI*DTR;
    const float* dpb  = dt_proj_b + (size_t)l*DI;
    const float* Alg  = A_log     + (size_t)l*DI*DSt;
    const float* Dpar = D_param   + (size_t)l*DI;
    const float* opw  = out_proj_w+ (size_t)l*DM*DI;

    ln_res_kernel<<<Bn*Ln/4, 256, 0, stream>>>(hb, resb, xb, lnw, lnb);
    gemm_mfma<bf16,0,0><<<dim3(24,24), 256, 0, stream>>>(xb, DM, ipw,
        nullptr, nullptr, nullptr, xz, 1536, Bn*Ln, 1536, DM);
    conv_save<<<Bn*3*NLC, 256, 0, stream>>>(xz, BND);
    conv_apply<<<Bn*3*NLC, 256, 0, stream>>>(xz, BND, cw, cb);
    gemm_mfma<float,0,0><<<dim3(24,1), 256, 0, stream>>>(xz, 1536, xpw,
        nullptr, nullptr, nullptr, xdb, 56, Bn*Ln, 56, DI);
    scanA_kernel<<<Bn*3*NCH, 256, 0, stream>>>(xz, xdb, dpw, dpb, Alg, SBS, SBdt);
    scanC_kernel<<<12, 256, 0, stream>>>(SBS, SBdt, Alg);
    scanB_kernel<<<Bn*3*NCH, 256, 0, stream>>>(xz, xdb, dpw, dpb, Alg, Dpar, SBS);
    gemm_mfma<float,0,1><<<dim3(24,6), 256, 0, stream>>>(xz, 1536, opw,
        nullptr, nullptr, nullptr, hb, DM, Bn*Ln, DM, DI);
  }

  final_ln_kernel<<<Bn*Ln/4, 256, 0, stream>>>(hb, resb, normf_w, normf_b, norm_w, norm_b, xf);
  head_kernel<<<Bn, 384, 0, stream>>>(xf, head_w1, head_b1, head_bn1_g, head_bn1_b,
                                      head_w2, head_b2, head_bn2_g, head_bn2_b,
                                      head_w3, head_b3, (float*)d_out);
}

// Round 8
// 2103.251 us; speedup vs baseline: 3.1789x; 1.1943x over previous
//
#include <hip/hip_runtime.h>
#include <hip/hip_bf16.h>

using bf16 = __hip_bfloat16;
using short8  = __attribute__((ext_vector_type(8))) short;
using floatx4 = __attribute__((ext_vector_type(4))) float;
using ull = unsigned long long;

constexpr int Bn = 4, Np = 1024, Gn = 128, Kn = 32;
constexpr int DM = 384, DEPTH = 12, CLSn = 40;
constexpr int DI = 768, DSt = 16, DTR = 24;
constexpr int Ln = 384;
constexpr int NCH = 12, CHS = 32;      // scan: 12 chunks x 32 steps
constexpr int NLC = 24;                // conv: 24 chunks x 16 steps
constexpr float EPSf = 1e-5f;
constexpr float BNS = 0.99999500003749968752f; // 1/sqrt(1+1e-5)
constexpr float LOG2E = 1.4426950408889634f;

static __device__ __forceinline__ short f2bf(float f){
  bf16 h = __float2bfloat16(f);
  return *reinterpret_cast<short*>(&h);
}
static __device__ __forceinline__ float fsig(float x){ return 1.f/(1.f + __expf(-x)); }
static __device__ __forceinline__ float fsoftplus(float x){
  return fmaxf(x, 0.f) + __logf(1.f + __expf(-fabsf(x)));
}
static __device__ __forceinline__ ull shfl_down_u64(ull v, int o){
  unsigned hi = (unsigned)(v >> 32), lo = (unsigned)v;
  unsigned h2 = __shfl_down(hi, o), l2 = __shfl_down(lo, o);
  return ((ull)h2 << 32) | l2;
}
static __device__ __forceinline__ ull shfl_u64(ull v, int lane){
  unsigned hi = (unsigned)(v >> 32), lo = (unsigned)v;
  unsigned h2 = __shfl(hi, lane), l2 = __shfl(lo, lane);
  return ((ull)h2 << 32) | l2;
}

// ---------------------------------------------------------------- FPS
// Single wave, fully register-resident. Distances via _rn ops (no FMA),
// order dx*dx+dy*dy+dz*dz. 64-bit key packs (dist_bits, 1023-n): max-reduce
// gives argmax with tie -> lowest global index (np.argmax semantics).
__global__ __launch_bounds__(64) void fps_kernel(const float* __restrict__ pts,
                                                 float* __restrict__ center){
  int b = blockIdx.x, t = threadIdx.x;
  const float* p = pts + (size_t)b * Np * 3;
  float X[16], Y[16], Z[16], D[16];
  #pragma unroll
  for (int i = 0; i < 16; ++i){
    int n = t + 64*i;
    X[i] = p[n*3+0]; Y[i] = p[n*3+1]; Z[i] = p[n*3+2];
    D[i] = 1e10f;
  }
  float px = __shfl(X[0], 0), py = __shfl(Y[0], 0), pz = __shfl(Z[0], 0);
  if (t == 0){
    center[(size_t)(b*Gn)*3+0] = px;
    center[(size_t)(b*Gn)*3+1] = py;
    center[(size_t)(b*Gn)*3+2] = pz;
  }
  for (int it = 1; it < Gn; ++it){
    float v = -1.f; int li = 0;
    #pragma unroll
    for (int i = 0; i < 16; ++i){
      float dx = __fsub_rn(X[i], px);
      float dy = __fsub_rn(Y[i], py);
      float dz = __fsub_rn(Z[i], pz);
      float d  = __fadd_rn(__fadd_rn(__fmul_rn(dx,dx), __fmul_rn(dy,dy)), __fmul_rn(dz,dz));
      float dm = fminf(D[i], d); D[i] = dm;
      if (dm > v){ v = dm; li = i; }   // ascending i: lowest n on tie within lane
    }
    int n = t + 64*li;
    ull key = ((ull)__float_as_uint(v) << 32) | (unsigned)(Np-1 - n);
    #pragma unroll
    for (int o = 32; o > 0; o >>= 1){
      ull k2 = shfl_down_u64(key, o);
      key = (k2 > key) ? k2 : key;     // ties impossible: low bits differ
    }
    key = shfl_u64(key, 0);
    int wn = Np-1 - (int)(key & 0xFFFFFFFFu);
    wn = min(max(wn, 0), Np-1);
    int wl = wn & 63, wi = wn >> 6;    // wi uniform across lanes
    // static-index select tree (register-resident) for this lane's point wi
    float ax[8], ay[8], az[8];
    #pragma unroll
    for (int i = 0; i < 8; ++i){
      ax[i] = (wi & 8) ? X[i+8] : X[i];
      ay[i] = (wi & 8) ? Y[i+8] : Y[i];
      az[i] = (wi & 8) ? Z[i+8] : Z[i];
    }
    float bx[4], by[4], bz[4];
    #pragma unroll
    for (int i = 0; i < 4; ++i){
      bx[i] = (wi & 4) ? ax[i+4] : ax[i];
      by[i] = (wi & 4) ? ay[i+4] : ay[i];
      bz[i] = (wi & 4) ? az[i+4] : az[i];
    }
    float cx[2], cy[2], cz[2];
    #pragma unroll
    for (int i = 0; i < 2; ++i){
      cx[i] = (wi & 2) ? bx[i+2] : bx[i];
      cy[i] = (wi & 2) ? by[i+2] : by[i];
      cz[i] = (wi & 2) ? bz[i+2] : bz[i];
    }
    float sx = (wi & 1) ? cx[1] : cx[0];
    float sy = (wi & 1) ? cy[1] : cy[0];
    float sz = (wi & 1) ? cz[1] : cz[0];
    px = __shfl(sx, wl); py = __shfl(sy, wl); pz = __shfl(sz, wl);
    if (t == 0){
      center[(size_t)(b*Gn+it)*3+0] = px;
      center[(size_t)(b*Gn+it)*3+1] = py;
      center[(size_t)(b*Gn+it)*3+2] = pz;
    }
  }
}

// ---------------------------------------------------------------- KNN
__global__ __launch_bounds__(256) void knn_kernel(const float* __restrict__ pts,
                                                  const float* __restrict__ center,
                                                  float* __restrict__ nb){
  int gid = blockIdx.x; int b = gid >> 7;
  __shared__ float d2[1024];
  __shared__ float rv[4]; __shared__ int ri[4];
  int t = threadIdx.x;
  float cx = center[(size_t)gid*3+0], cy = center[(size_t)gid*3+1], cz = center[(size_t)gid*3+2];
  const float* p = pts + (size_t)b * Np * 3;
  for (int n = t; n < Np; n += 256){
    float dx = __fsub_rn(cx, p[n*3+0]);
    float dy = __fsub_rn(cy, p[n*3+1]);
    float dz = __fsub_rn(cz, p[n*3+2]);
    d2[n] = __fadd_rn(__fadd_rn(__fmul_rn(dx,dx), __fmul_rn(dy,dy)), __fmul_rn(dz,dz));
  }
  __syncthreads();
  for (int kk = 0; kk < Kn; ++kk){
    float v = 3e38f; int idx = 0;
    for (int n = t; n < Np; n += 256){
      float d = d2[n];
      if (d < v || (d == v && n < idx)){ v = d; idx = n; }
    }
    #pragma unroll
    for (int o = 32; o > 0; o >>= 1){
      float v2 = __shfl_down(v, o); int i2 = __shfl_down(idx, o);
      if (v2 < v || (v2 == v && i2 < idx)){ v = v2; idx = i2; }
    }
    if ((t & 63) == 0){ rv[t>>6] = v; ri[t>>6] = idx; }
    __syncthreads();
    if (t == 0){
      float bv = rv[0]; int bi = ri[0];
      for (int w = 1; w < 4; ++w){
        if (rv[w] < bv || (rv[w] == bv && ri[w] < bi)){ bv = rv[w]; bi = ri[w]; }
      }
      bi = min(max(bi, 0), Np-1);
      nb[((size_t)gid*Kn+kk)*3+0] = __fsub_rn(p[bi*3+0], cx);
      nb[((size_t)gid*Kn+kk)*3+1] = __fsub_rn(p[bi*3+1], cy);
      nb[((size_t)gid*Kn+kk)*3+2] = __fsub_rn(p[bi*3+2], cz);
      d2[bi] = 3e38f;
    }
    __syncthreads();
  }
}

// ---------------------------------------------------------------- MFMA GEMM
// C[M,N] = act(A[M,K](lda) @ W[N,K]^T + bias). bf16 MFMA, fp32 accumulate.
// GATE: A element = y[m,k] * silu(z[m,k]) with z at A col offset +768.
template<typename AT, int ACT, int GATE>
__global__ __launch_bounds__(256) void gemm_mfma(const AT* __restrict__ A, int lda,
                                                 const float* __restrict__ W,
                                                 const float* __restrict__ bias,
                                                 const float* __restrict__ g,
                                                 const float* __restrict__ bb,
                                                 float* __restrict__ C, int ldc,
                                                 int M, int N, int K){
  __shared__ __align__(16) short As[64*40];
  __shared__ __align__(16) short Ws[64*40];
  int bm = blockIdx.x * 64, bn = blockIdx.y * 64;
  int t = threadIdx.x;
  int row = t >> 2;
  int kseg = (t & 3) * 8;
  int w = t >> 6, lane = t & 63, m16 = lane & 15, q = lane >> 4;
  bool kvec = ((K & 3) == 0) && ((lda & 3) == 0 || sizeof(AT) == 2);
  floatx4 acc[4] = {};
  for (int k0 = 0; k0 < K; k0 += 32){
    if constexpr (GATE){
      const float* Ar = (const float*)A + (size_t)(bm + row)*lda + k0 + kseg;
      float4 y0 = *(const float4*)Ar;
      float4 y1 = *(const float4*)(Ar + 4);
      float4 z0 = *(const float4*)(Ar + 768);
      float4 z1 = *(const float4*)(Ar + 772);
      short* dst = &As[row*40 + kseg];
      dst[0] = f2bf(y0.x * (z0.x * fsig(z0.x)));
      dst[1] = f2bf(y0.y * (z0.y * fsig(z0.y)));
      dst[2] = f2bf(y0.z * (z0.z * fsig(z0.z)));
      dst[3] = f2bf(y0.w * (z0.w * fsig(z0.w)));
      dst[4] = f2bf(y1.x * (z1.x * fsig(z1.x)));
      dst[5] = f2bf(y1.y * (z1.y * fsig(z1.y)));
      dst[6] = f2bf(y1.z * (z1.z * fsig(z1.z)));
      dst[7] = f2bf(y1.w * (z1.w * fsig(z1.w)));
    } else if constexpr (sizeof(AT) == 2){
      *(short8*)&As[row*40 + kseg] =
          *(const short8*)((const short*)A + (size_t)(bm + row)*lda + k0 + kseg);
    } else {
      const float* Ar = (const float*)A + (size_t)(bm + row)*lda;
      short* dst = &As[row*40 + kseg];
      if (kvec && (k0 + kseg + 8 <= K)){
        float4 a0 = *(const float4*)(Ar + k0 + kseg);
        float4 a1 = *(const float4*)(Ar + k0 + kseg + 4);
        dst[0]=f2bf(a0.x); dst[1]=f2bf(a0.y); dst[2]=f2bf(a0.z); dst[3]=f2bf(a0.w);
        dst[4]=f2bf(a1.x); dst[5]=f2bf(a1.y); dst[6]=f2bf(a1.z); dst[7]=f2bf(a1.w);
      } else {
        #pragma unroll
        for (int j = 0; j < 8; ++j){
          int k = k0 + kseg + j;
          dst[j] = (k < K) ? f2bf(Ar[k]) : (short)0;
        }
      }
    }
    {
      int n = bn + row;
      short* dst = &Ws[row*40 + kseg];
      if (n < N && ((K & 3) == 0) && (k0 + kseg + 8 <= K)){
        const float* Wr = W + (size_t)n*K + k0 + kseg;
        float4 w0 = *(const float4*)Wr;
        float4 w1 = *(const float4*)(Wr + 4);
        dst[0]=f2bf(w0.x); dst[1]=f2bf(w0.y); dst[2]=f2bf(w0.z); dst[3]=f2bf(w0.w);
        dst[4]=f2bf(w1.x); dst[5]=f2bf(w1.y); dst[6]=f2bf(w1.z); dst[7]=f2bf(w1.w);
      } else {
        #pragma unroll
        for (int j = 0; j < 8; ++j){
          int k = k0 + kseg + j;
          dst[j] = (n < N && k < K) ? f2bf(W[(size_t)n*K + k]) : (short)0;
        }
      }
    }
    __syncthreads();
    short8 af = *(const short8*)&As[(w*16 + m16)*40 + q*8];
    #pragma unroll
    for (int j = 0; j < 4; ++j){
      short8 bfr = *(const short8*)&Ws[(j*16 + m16)*40 + q*8];
      acc[j] = __builtin_amdgcn_mfma_f32_16x16x32_bf16(af, bfr, acc[j], 0, 0, 0);
    }
    __syncthreads();
  }
  #pragma unroll
  for (int j = 0; j < 4; ++j){
    int n = bn + j*16 + m16;
    if (n < N){
      float bv = bias ? bias[n] : 0.f;
      float gv = 0.f, bbv = 0.f;
      if (ACT == 1){ gv = g[n] * BNS; bbv = bb[n]; }
      #pragma unroll
      for (int r = 0; r < 4; ++r){
        int m = bm + w*16 + q*4 + r;
        float v = acc[j][r] + bv;
        if (ACT == 1){ v = v * gv + bbv; v = fmaxf(v, 0.f); }
        C[(size_t)m*ldc + n] = v;
      }
    }
  }
}

// -------------------------------------------------- encoder max-pools
__global__ __launch_bounds__(256) void maxk_fg(float* __restrict__ f3in){
  int gg = blockIdx.x; int c = threadIdx.x;
  float m = -3e38f;
  for (int k = 0; k < Kn; ++k) m = fmaxf(m, f3in[((size_t)gg*Kn + k)*512 + 256 + c]);
  for (int k = 0; k < Kn; ++k) f3in[((size_t)gg*Kn + k)*512 + c] = m;
}

__global__ __launch_bounds__(384) void maxk_tok(const float* __restrict__ f4, float* __restrict__ tok){
  int gg = blockIdx.x; int c = threadIdx.x;
  float m = -3e38f;
  for (int k = 0; k < Kn; ++k) m = fmaxf(m, f4[((size_t)gg*Kn + k)*DM + c]);
  tok[(size_t)gg*DM + c] = m;
}

// -------------------------------------------------- pos embedding (adds into tok)
__global__ __launch_bounds__(128) void pos_kernel(const float* __restrict__ center,
                                                  const float* __restrict__ w1, const float* __restrict__ b1,
                                                  const float* __restrict__ w2, const float* __restrict__ b2,
                                                  float* __restrict__ tok){
  int gid = blockIdx.x;
  __shared__ float h1[128]; __shared__ float c3[3];
  int t = threadIdx.x;
  if (t < 3) c3[t] = center[(size_t)gid*3 + t];
  __syncthreads();
  float a = w1[t*3+0]*c3[0] + w1[t*3+1]*c3[1] + w1[t*3+2]*c3[2] + b1[t];
  h1[t] = 0.5f * a * (1.f + erff(a * 0.70710678118654752440f));
  __syncthreads();
  for (int c = t; c < DM; c += 128){
    float s = b2[c];
    for (int j = 0; j < 128; ++j) s += w2[(size_t)c*128 + j] * h1[j];
    tok[(size_t)gid*DM + c] += s;
  }
}

// -------------------------------------------------- stable argsort (rank count)
__global__ __launch_bounds__(128) void sort_kernel(const float* __restrict__ center,
                                                   int* __restrict__ order){
  int bax = blockIdx.x; int b = bax / 3, ax = bax % 3;
  __shared__ float key[128];
  int t = threadIdx.x;
  key[t] = center[(size_t)(b*Gn + t)*3 + ax];
  __syncthreads();
  float kt = key[t]; int r = 0;
  for (int j = 0; j < Gn; ++j){
    float kj = key[j];
    r += (kj < kt || (kj == kt && j < t)) ? 1 : 0;
  }
  r = min(max(r, 0), Gn-1);
  order[b*Ln + ax*Gn + r] = t;
}

// -------------------------------------------------- token gather + res init
__global__ __launch_bounds__(256) void build_h(const float* __restrict__ tok,
                        const int* __restrict__ order,
                        float* __restrict__ h, float* __restrict__ res){
  int i = blockIdx.x * blockDim.x + threadIdx.x;
  if (i >= Bn*Ln*DM) return;
  int c = i % DM; int l = (i / DM) % Ln; int b = i / (DM*Ln);
  int src = order[b*Ln + l];
  src = min(max(src, 0), Gn-1);
  h[i] = tok[((size_t)(b*Gn + src))*DM + c];
  res[i] = 0.f;
}

// -------------------------------------------------- res += h; x = LN(res)*w+b (bf16 out)
__global__ __launch_bounds__(256) void ln_res_kernel(const float* __restrict__ h,
                                                     float* __restrict__ res,
                                                     bf16* __restrict__ x,
                                                     const float* __restrict__ w,
                                                     const float* __restrict__ bias){
  int wv = threadIdx.x >> 6, ln = threadIdx.x & 63;
  int tokid = blockIdx.x*4 + wv;
  const float* hr = h + (size_t)tokid*DM;
  float* rr = res + (size_t)tokid*DM;
  bf16* xr = x + (size_t)tokid*DM;
  float v[6]; float s = 0.f;
  #pragma unroll
  for (int i = 0; i < 6; ++i){ int c = ln + 64*i; float t = hr[c] + rr[c]; rr[c] = t; v[i] = t; s += t; }
  #pragma unroll
  for (int o = 32; o > 0; o >>= 1) s += __shfl_xor(s, o);
  float mu = s * (1.f/DM);
  float q = 0.f;
  #pragma unroll
  for (int i = 0; i < 6; ++i){ float d = v[i] - mu; q += d*d; }
  #pragma unroll
  for (int o = 32; o > 0; o >>= 1) q += __shfl_xor(q, o);
  float rstd = rsqrtf(q * (1.f/DM) + EPSf);
  #pragma unroll
  for (int i = 0; i < 6; ++i){ int c = ln + 64*i;
    xr[c] = __float2bfloat16((v[i]-mu)*rstd*w[c] + bias[c]); }
}

// -------------------------------------------------- conv pass 1: save boundaries
__global__ __launch_bounds__(256) void conv_save(const float* __restrict__ xz,
                                                 float* __restrict__ bnd){
  int blk = blockIdx.x;
  int lc = blk % NLC; int bd = blk / NLC; int dch = bd % 3; int b = bd / 3;
  int t = threadIdx.x; int d = dch*256 + t;
  int l0 = lc*16;
  #pragma unroll
  for (int j = 0; j < 3; ++j){
    int l = l0 - 3 + j;
    float v = (l >= 0) ? xz[((size_t)(b*Ln + l))*1536 + d] : 0.f;
    bnd[(((size_t)blk)*3 + j)*256 + t] = v;
  }
}

// -------------------------------------------------- conv pass 2: FIR + silu (in place)
__global__ __launch_bounds__(256) void conv_apply(float* __restrict__ xz,
                                                  const float* __restrict__ bnd,
                                                  const float* __restrict__ cw,
                                                  const float* __restrict__ cb){
  int blk = blockIdx.x;
  int lc = blk % NLC; int bd = blk / NLC; int dch = bd % 3; int b = bd / 3;
  int t = threadIdx.x; int d = dch*256 + t;
  int l0 = lc*16;
  float w0 = cw[d*4+0], w1 = cw[d*4+1], w2 = cw[d*4+2], w3 = cw[d*4+3];
  float bias = cb[d];
  float u0 = bnd[(((size_t)blk)*3 + 0)*256 + t];
  float u1 = bnd[(((size_t)blk)*3 + 1)*256 + t];
  float u2 = bnd[(((size_t)blk)*3 + 2)*256 + t];
  float* p = xz + ((size_t)(b*Ln + l0))*1536 + d;
  float r[16];
  #pragma unroll
  for (int i = 0; i < 16; ++i) r[i] = p[(size_t)i*1536];
  #pragma unroll
  for (int i = 0; i < 16; ++i){
    float v = u0*w0 + u1*w1 + u2*w2 + r[i]*w3 + bias;
    p[(size_t)i*1536] = v * fsig(v);
    u0 = u1; u1 = u2; u2 = r[i];
  }
}

// -------------------------------------------------- chunked selective scan
// Phase A: per (b,dch,chunk) block, local scan from h=0 -> S[16], sum dt.
__global__ __launch_bounds__(256) void scanA_kernel(const float* __restrict__ xz,
                                                    const float* __restrict__ xdb,
                                                    const float* __restrict__ dpw,
                                                    const float* __restrict__ dpb,
                                                    const float* __restrict__ A_log,
                                                    float* __restrict__ SB_S,
                                                    float* __restrict__ SB_dt){
  __shared__ float sRow[CHS*56];
  __shared__ float sU[CHS*256];
  int blk = blockIdx.x;
  int c = blk % NCH; int bd = blk / NCH; int dch = bd % 3; int b = bd / 3;
  int t = threadIdx.x; int d = dch*256 + t;
  int l0 = c*CHS;
  for (int i = t; i < CHS*56; i += 256) sRow[i] = xdb[((size_t)(b*Ln + l0))*56 + i];
  const float* xzu = xz + ((size_t)(b*Ln + l0))*1536 + dch*256;
  #pragma unroll
  for (int i = 0; i < CHS; ++i) sU[i*256 + t] = xzu[(size_t)i*1536 + t];
  float w[DTR];
  const float* wp = dpw + (size_t)d*DTR;
  #pragma unroll
  for (int j = 0; j < DTR; ++j) w[j] = wp[j];
  float a2[DSt], h[DSt];
  const float* ap = A_log + (size_t)d*DSt;
  #pragma unroll
  for (int s = 0; s < DSt; ++s){ a2[s] = -__expf(ap[s]) * LOG2E; h[s] = 0.f; }
  float dbias = dpb[d];
  float sumdt = 0.f;
  __syncthreads();
  for (int i = 0; i < CHS; ++i){
    int ro = i*56;
    float dtr = dbias;
    #pragma unroll
    for (int j = 0; j < DTR; ++j) dtr += w[j] * sRow[ro + j];
    float dtv = fsoftplus(dtr);
    sumdt += dtv;
    float du = dtv * sU[i*256 + t];
    #pragma unroll
    for (int s = 0; s < DSt; ++s)
      h[s] = exp2f(dtv * a2[s]) * h[s] + du * sRow[ro + 24 + s];
  }
  size_t sb = ((size_t)blk*256 + t)*16;
  #pragma unroll
  for (int s = 0; s < DSt; ++s) SB_S[sb + s] = h[s];
  SB_dt[(size_t)blk*256 + t] = sumdt;
}

// Phase B (combine fused): h_in = prefix over earlier chunks, then re-run chunk,
// write UNGATED y in place (gate applied in out_proj staging).
__global__ __launch_bounds__(256) void scanB_kernel(float* __restrict__ xz,
                                                    const float* __restrict__ xdb,
                                                    const float* __restrict__ dpw,
                                                    const float* __restrict__ dpb,
                                                    const float* __restrict__ A_log,
                                                    const float* __restrict__ Dp,
                                                    const float* __restrict__ SB_S,
                                                    const float* __restrict__ SB_dt){
  __shared__ float sRow[CHS*56];
  __shared__ float sU[CHS*256];
  int blk = blockIdx.x;
  int c = blk % NCH; int bd = blk / NCH; int dch = bd % 3; int b = bd / 3;
  int t = threadIdx.x; int d = dch*256 + t;
  int l0 = c*CHS;
  for (int i = t; i < CHS*56; i += 256) sRow[i] = xdb[((size_t)(b*Ln + l0))*56 + i];
  float* xzu = xz + ((size_t)(b*Ln + l0))*1536 + dch*256;
  #pragma unroll
  for (int i = 0; i < CHS; ++i) sU[i*256 + t] = xzu[(size_t)i*1536 + t];
  float w[DTR];
  const float* wp = dpw + (size_t)d*DTR;
  #pragma unroll
  for (int j = 0; j < DTR; ++j) w[j] = wp[j];
  float a2[DSt], h[DSt];
  const float* ap = A_log + (size_t)d*DSt;
  #pragma unroll
  for (int s = 0; s < DSt; ++s){ a2[s] = -__expf(ap[s]) * LOG2E; h[s] = 0.f; }
  // fused combine: sequential prefix over chunks < c (identical order to scanC)
  for (int cc = 0; cc < c; ++cc){
    size_t base = (((size_t)bd*NCH + cc)*256 + t)*16;
    float sd = SB_dt[((size_t)bd*NCH + cc)*256 + t];
    #pragma unroll
    for (int s = 0; s < DSt; ++s)
      h[s] = exp2f(sd * a2[s]) * h[s] + SB_S[base + s];
  }
  float dbias = dpb[d];
  float Dd = Dp[d];
  __syncthreads();
  for (int i = 0; i < CHS; ++i){
    int ro = i*56;
    float dtr = dbias;
    #pragma unroll
    for (int j = 0; j < DTR; ++j) dtr += w[j] * sRow[ro + j];
    float dtv = fsoftplus(dtr);
    float u = sU[i*256 + t];
    float du = dtv * u;
    float yv = 0.f;
    #pragma unroll
    for (int s = 0; s < DSt; ++s){
      h[s] = exp2f(dtv * a2[s]) * h[s] + du * sRow[ro + 24 + s];
      yv += h[s] * sRow[ro + 40 + s];
    }
    xzu[(size_t)i*1536 + t] = yv + u*Dd;
  }
}

// -------------------------------------------------- final two LayerNorms
__global__ __launch_bounds__(256) void final_ln_kernel(const float* __restrict__ h,
                                                       const float* __restrict__ res,
                                                       const float* w1, const float* b1,
                                                       const float* w2, const float* b2,
                                                       float* __restrict__ x){
  int wv = threadIdx.x >> 6, ln = threadIdx.x & 63;
  int tokid = blockIdx.x*4 + wv;
  const float* hr = h + (size_t)tokid*DM;
  const float* rr = res + (size_t)tokid*DM;
  float* xr = x + (size_t)tokid*DM;
  float v[6]; float s = 0.f;
  #pragma unroll
  for (int i = 0; i < 6; ++i){ int c = ln + 64*i; v[i] = hr[c] + rr[c]; s += v[i]; }
  #pragma unroll
  for (int o = 32; o > 0; o >>= 1) s += __shfl_xor(s, o);
  float mu = s * (1.f/DM); float q = 0.f;
  #pragma unroll
  for (int i = 0; i < 6; ++i){ float dd = v[i]-mu; q += dd*dd; }
  #pragma unroll
  for (int o = 32; o > 0; o >>= 1) q += __shfl_xor(q, o);
  float rstd = rsqrtf(q * (1.f/DM) + EPSf);
  float u[6]; float s2 = 0.f;
  #pragma unroll
  for (int i = 0; i < 6; ++i){ int c = ln + 64*i; u[i] = (v[i]-mu)*rstd*w1[c] + b1[c]; s2 += u[i]; }
  #pragma unroll
  for (int o = 32; o > 0; o >>= 1) s2 += __shfl_xor(s2, o);
  float mu2 = s2 * (1.f/DM); float q2 = 0.f;
  #pragma unroll
  for (int i = 0; i < 6; ++i){ float dd = u[i]-mu2; q2 += dd*dd; }
  #pragma unroll
  for (int o = 32; o > 0; o >>= 1) q2 += __shfl_xor(q2, o);
  float rstd2 = rsqrtf(q2 * (1.f/DM) + EPSf);
  #pragma unroll
  for (int i = 0; i < 6; ++i){ int c = ln + 64*i; xr[c] = (u[i]-mu2)*rstd2*w2[c] + b2[c]; }
}

// -------------------------------------------------- mean over L + MLP head
__global__ __launch_bounds__(384) void head_kernel(const float* __restrict__ x,
    const float* w1, const float* b1, const float* g1, const float* bb1,
    const float* w2, const float* b2, const float* g2, const float* bb2,
    const float* w3, const float* b3, float* __restrict__ out){
  int b = blockIdx.x; int t = threadIdx.x;
  __shared__ float feat[DM]; __shared__ float h1[256]; __shared__ float h2[256];
  float s = 0.f;
  for (int l = 0; l < Ln; ++l) s += x[((size_t)(b*Ln + l))*DM + t];
  feat[t] = s * (1.f/Ln);
  __syncthreads();
  if (t < 256){
    float a = b1[t];
    for (int j = 0; j < DM; ++j) a += w1[(size_t)t*DM + j] * feat[j];
    a = a * (g1[t] * BNS) + bb1[t];
    h1[t] = fmaxf(a, 0.f);
  }
  __syncthreads();
  if (t < 256){
    float a = b2[t];
    for (int j = 0; j < 256; ++j) a += w2[(size_t)t*256 + j] * h1[j];
    a = a * (g2[t] * BNS) + bb2[t];
    h2[t] = fmaxf(a, 0.f);
  }
  __syncthreads();
  if (t < CLSn){
    float a = b3[t];
    for (int j = 0; j < 256; ++j) a += w3[(size_t)t*256 + j] * h2[j];
    out[b*CLSn + t] = a;
  }
}

extern "C" void kernel_launch(void* const* d_in, const int* in_sizes, int n_in,
                              void* d_out, int out_size, void* d_ws, size_t ws_size,
                              hipStream_t stream) {
  if (n_in < 42) return;
  if (out_size < Bn*CLSn) return;
  constexpr size_t WS_FLOATS = 3919936;
  if (ws_size < WS_FLOATS * sizeof(float)) return;
  // big-path encoder buffers live beyond the base region
  constexpr size_t BIG_BASE = 3919936;
  constexpr size_t BIG_FLOATS = 8388608 + 8388608 + 2097152; // F3in,F3,F1 (F4 aliases F3in)
  const bool big = ws_size >= (BIG_BASE + BIG_FLOATS) * sizeof(float);

  const float* pts       = (const float*)d_in[0];
  const float* enc_w1    = (const float*)d_in[1];  const float* enc_b1    = (const float*)d_in[2];
  const float* enc_bn1_g = (const float*)d_in[3];  const float* enc_bn1_b = (const float*)d_in[4];
  const float* enc_w2    = (const float*)d_in[5];  const float* enc_b2    = (const float*)d_in[6];
  const float* enc_w3    = (const float*)d_in[7];  const float* enc_b3    = (const float*)d_in[8];
  const float* enc_bn2_g = (const float*)d_in[9];  const float* enc_bn2_b = (const float*)d_in[10];
  const float* enc_w4    = (const float*)d_in[11]; const float* enc_b4    = (const float*)d_in[12];
  const float* pos_w1    = (const float*)d_in[13]; const float* pos_b1    = (const float*)d_in[14];
  const float* pos_w2    = (const float*)d_in[15]; const float* pos_b2    = (const float*)d_in[16];
  const float* ln_w      = (const float*)d_in[17]; const float* ln_b      = (const float*)d_in[18];
  const float* in_proj_w = (const float*)d_in[19];
  const float* conv_w    = (const float*)d_in[20]; const float* conv_b    = (const float*)d_in[21];
  const float* x_proj_w  = (const float*)d_in[22];
  const float* dt_proj_w = (const float*)d_in[23]; const float* dt_proj_b = (const float*)d_in[24];
  const float* A_log     = (const float*)d_in[25]; const float* D_param   = (const float*)d_in[26];
  const float* out_proj_w= (const float*)d_in[27];
  const float* normf_w   = (const float*)d_in[28]; const float* normf_b   = (const float*)d_in[29];
  const float* norm_w    = (const float*)d_in[30]; const float* norm_b    = (const float*)d_in[31];
  const float* head_w1   = (const float*)d_in[32]; const float* head_b1   = (const float*)d_in[33];
  const float* head_bn1_g= (const float*)d_in[34]; const float* head_bn1_b= (const float*)d_in[35];
  const float* head_w2   = (const float*)d_in[36]; const float* head_b2   = (const float*)d_in[37];
  const float* head_bn2_g= (const float*)d_in[38]; const float* head_bn2_b= (const float*)d_in[39];
  const float* head_w3   = (const float*)d_in[40]; const float* head_b3   = (const float*)d_in[41];

  float* ws = (float*)d_ws;
  float* hb   = ws;                   // 589,824 floats
  float* resb = ws + 589824;          // 589,824
  float* U    = ws + 1179648;         // 2,740,224
  // setup/encoder view of U
  float* center = U;
  float* nb     = U + 1536;
  float* tok    = U + 50688;
  int*   order  = (int*)(U + 247296);
  float* eb0    = U + 262144;
  float* eb1    = U + 1310720;
  // mamba view of U
  float* xz   = U;                      // 2,359,296 (1536 x 1536)
  float* xdb  = U + 2359296;            // 86,016
  bf16*  xb   = (bf16*)(U + 2445312);   // 589,824 bf16 in 294,912 float slots
  float* SBdt = U + 2445312;            // 36,864 (xb dead when scanA runs)
  float* BND  = U + 2482176;            // 221,184
  float* SBS  = hb;                     // 589,824 (hb dead between ln_res and out_proj)
  float* xf   = U;
  // big-path encoder buffers
  float* F3in = ws + BIG_BASE;          // 8,388,608 (16384 x 512); F4 aliases
  float* F3   = ws + BIG_BASE + 8388608;
  float* F1   = ws + BIG_BASE + 16777216;
  float* F4   = F3in;

  fps_kernel<<<Bn, 64, 0, stream>>>(pts, center);
  knn_kernel<<<Bn*Gn, 256, 0, stream>>>(pts, center, nb);

  if (big){
    gemm_mfma<float,1,0><<<dim3(256,2), 256, 0, stream>>>(nb, 3, enc_w1, enc_b1,
        enc_bn1_g, enc_bn1_b, F1, 128, 16384, 128, 3);
    gemm_mfma<float,0,0><<<dim3(256,4), 256, 0, stream>>>(F1, 128, enc_w2, enc_b2,
        nullptr, nullptr, F3in + 256, 512, 16384, 256, 128);
    maxk_fg<<<512, 256, 0, stream>>>(F3in);
    gemm_mfma<float,1,0><<<dim3(256,8), 256, 0, stream>>>(F3in, 512, enc_w3, enc_b3,
        enc_bn2_g, enc_bn2_b, F3, 512, 16384, 512, 512);
    gemm_mfma<float,0,0><<<dim3(256,6), 256, 0, stream>>>(F3, 512, enc_w4, enc_b4,
        nullptr, nullptr, F4, 384, 16384, 384, 512);
    maxk_tok<<<512, 384, 0, stream>>>(F4, tok);
  } else {
    for (int ch = 0; ch < 8; ++ch){
      const float* nb_c = nb + (size_t)ch*2048*3;
      float* tok_c = tok + (size_t)ch*64*DM;
      gemm_mfma<float,1,0><<<dim3(32,2), 256, 0, stream>>>(nb_c, 3, enc_w1, enc_b1,
          enc_bn1_g, enc_bn1_b, eb1, 128, 2048, 128, 3);
      gemm_mfma<float,0,0><<<dim3(32,4), 256, 0, stream>>>(eb1, 128, enc_w2, enc_b2,
          nullptr, nullptr, eb0 + 256, 512, 2048, 256, 128);
      maxk_fg<<<64, 256, 0, stream>>>(eb0);
      gemm_mfma<float,1,0><<<dim3(32,8), 256, 0, stream>>>(eb0, 512, enc_w3, enc_b3,
          enc_bn2_g, enc_bn2_b, eb1, 512, 2048, 512, 512);
      gemm_mfma<float,0,0><<<dim3(32,6), 256, 0, stream>>>(eb1, 512, enc_w4, enc_b4,
          nullptr, nullptr, eb0, 384, 2048, 384, 512);
      maxk_tok<<<64, 384, 0, stream>>>(eb0, tok_c);
    }
  }

  pos_kernel<<<Bn*Gn, 128, 0, stream>>>(center, pos_w1, pos_b1, pos_w2, pos_b2, tok);
  sort_kernel<<<Bn*3, 128, 0, stream>>>(center, order);
  build_h<<<(Bn*Ln*DM + 255)/256, 256, 0, stream>>>(tok, order, hb, resb);

  for (int l = 0; l < DEPTH; ++l){
    const float* lnw  = ln_w      + (size_t)l*DM;
    const float* lnb  = ln_b      + (size_t)l*DM;
    const float* ipw  = in_proj_w + (size_t)l*1536*DM;
    const float* cw   = conv_w    + (size_t)l*DI*4;
    const float* cb   = conv_b    + (size_t)l*DI;
    const float* xpw  = x_proj_w  + (size_t)l*56*DI;
    const float* dpw  = dt_proj_w + (size_t)l*DI*DTR;
    const float* dpb  = dt_proj_b + (size_t)l*DI;
    const float* Alg  = A_log     + (size_t)l*DI*DSt;
    const float* Dpar = D_param   + (size_t)l*DI;
    const float* opw  = out_proj_w+ (size_t)l*DM*DI;

    ln_res_kernel<<<Bn*Ln/4, 256, 0, stream>>>(hb, resb, xb, lnw, lnb);
    gemm_mfma<bf16,0,0><<<dim3(24,24), 256, 0, stream>>>(xb, DM, ipw,
        nullptr, nullptr, nullptr, xz, 1536, Bn*Ln, 1536, DM);
    conv_save<<<Bn*3*NLC, 256, 0, stream>>>(xz, BND);
    conv_apply<<<Bn*3*NLC, 256, 0, stream>>>(xz, BND, cw, cb);
    gemm_mfma<float,0,0><<<dim3(24,1), 256, 0, stream>>>(xz, 1536, xpw,
        nullptr, nullptr, nullptr, xdb, 56, Bn*Ln, 56, DI);
    scanA_kernel<<<Bn*3*NCH, 256, 0, stream>>>(xz, xdb, dpw, dpb, Alg, SBS, SBdt);
    scanB_kernel<<<Bn*3*NCH, 256, 0, stream>>>(xz, xdb, dpw, dpb, Alg, Dpar, SBS, SBdt);
    gemm_mfma<float,0,1><<<dim3(24,6), 256, 0, stream>>>(xz, 1536, opw,
        nullptr, nullptr, nullptr, hb, DM, Bn*Ln, DM, DI);
  }

  final_ln_kernel<<<Bn*Ln/4, 256, 0, stream>>>(hb, resb, normf_w, normf_b, norm_w, norm_b, xf);
  head_kernel<<<Bn, 384, 0, stream>>>(xf, head_w1, head_b1, head_bn1_g, head_bn1_b,
                                      head_w2, head_b2, head_bn2_g, head_bn2_b,
                                      head_w3, head_b3, (float*)d_out);
}

// Round 9
// 2036.603 us; speedup vs baseline: 3.2829x; 1.0327x over previous
//
#include <hip/hip_runtime.h>
#include <hip/hip_bf16.h>

using bf16 = __hip_bfloat16;
using short8  = __attribute__((ext_vector_type(8))) short;
using floatx4 = __attribute__((ext_vector_type(4))) float;
using ull = unsigned long long;

constexpr int Bn = 4, Np = 1024, Gn = 128, Kn = 32;
constexpr int DM = 384, DEPTH = 12, CLSn = 40;
constexpr int DI = 768, DSt = 16, DTR = 24;
constexpr int Ln = 384;
constexpr int NCH = 12, CHS = 32;      // scan: 12 chunks x 32 steps
constexpr int NLC = 24;                // conv: 24 chunks x 16 steps
constexpr float EPSf = 1e-5f;
constexpr float BNS = 0.99999500003749968752f; // 1/sqrt(1+1e-5)
constexpr float LOG2E = 1.4426950408889634f;

static __device__ __forceinline__ short f2bf(float f){
  bf16 h = __float2bfloat16(f);
  return *reinterpret_cast<short*>(&h);
}
static __device__ __forceinline__ float fsig(float x){ return 1.f/(1.f + __expf(-x)); }
static __device__ __forceinline__ float fsoftplus(float x){
  return fmaxf(x, 0.f) + __logf(1.f + __expf(-fabsf(x)));
}

// DPP lane move (VALU-latency, no LDS). bound_ctrl=true -> invalid lanes read 0.
template<int CTRL>
static __device__ __forceinline__ int dppmov(int x){
  return __builtin_amdgcn_update_dpp(0, x, CTRL, 0xF, 0xF, true);
}
// 64-bit unsigned max reduce to lane 63 via DPP (row_shr 1/2/4/8, bcast15, bcast31).
static __device__ __forceinline__ ull redmax64(ull key){
  #define RSTEP(CTRL) { \
    int hi = (int)(unsigned)(key >> 32), lo = (int)(unsigned)key; \
    int h2 = dppmov<CTRL>(hi), l2 = dppmov<CTRL>(lo); \
    ull k2 = ((ull)(unsigned)h2 << 32) | (unsigned)l2; \
    if (k2 > key) key = k2; }
  RSTEP(0x111) RSTEP(0x112) RSTEP(0x114) RSTEP(0x118) RSTEP(0x142) RSTEP(0x143)
  #undef RSTEP
  return key;  // lane 63 holds the wave max
}

// ---------------------------------------------------------------- FPS
// Single wave, register-resident. _rn distance math, order dx*dx+dy*dy+dz*dz.
// key = (dist_bits<<32)|(1023-n): DPP max-reduce = argmax, tie -> lowest n.
__global__ __launch_bounds__(64, 1) void fps_kernel(const float* __restrict__ pts,
                                                    float* __restrict__ center){
  int b = blockIdx.x, t = threadIdx.x;
  const float* p = pts + (size_t)b * Np * 3;
  float X[16], Y[16], Z[16], D[16];
  #pragma unroll
  for (int i = 0; i < 16; ++i){
    int n = t + 64*i;
    X[i] = p[n*3+0]; Y[i] = p[n*3+1]; Z[i] = p[n*3+2];
    D[i] = 1e10f;
  }
  float px = __uint_as_float(__builtin_amdgcn_readlane(__float_as_uint(X[0]), 0));
  float py = __uint_as_float(__builtin_amdgcn_readlane(__float_as_uint(Y[0]), 0));
  float pz = __uint_as_float(__builtin_amdgcn_readlane(__float_as_uint(Z[0]), 0));
  if (t == 0){
    center[(size_t)(b*Gn)*3+0] = px;
    center[(size_t)(b*Gn)*3+1] = py;
    center[(size_t)(b*Gn)*3+2] = pz;
  }
  for (int it = 1; it < Gn; ++it){
    float v = -1.f; int li = 0;
    #pragma unroll
    for (int i = 0; i < 16; ++i){
      float dx = __fsub_rn(X[i], px);
      float dy = __fsub_rn(Y[i], py);
      float dz = __fsub_rn(Z[i], pz);
      float d  = __fadd_rn(__fadd_rn(__fmul_rn(dx,dx), __fmul_rn(dy,dy)), __fmul_rn(dz,dz));
      float dm = fminf(D[i], d); D[i] = dm;
      if (dm > v){ v = dm; li = i; }   // ascending i: lowest n on tie within lane
    }
    int n = t + 64*li;
    ull key = ((ull)__float_as_uint(v) << 32) | (unsigned)(Np-1 - n);
    key = redmax64(key);
    int lo63 = __builtin_amdgcn_readlane((int)(unsigned)(key & 0xFFFFFFFFu), 63);
    int wn = Np-1 - lo63;
    wn = min(max(wn, 0), Np-1);
    int wl = wn & 63, wi = wn >> 6;    // both wave-uniform
    // static-index select tree for point wi within each lane
    float ax[8], ay[8], az[8];
    #pragma unroll
    for (int i = 0; i < 8; ++i){
      ax[i] = (wi & 8) ? X[i+8] : X[i];
      ay[i] = (wi & 8) ? Y[i+8] : Y[i];
      az[i] = (wi & 8) ? Z[i+8] : Z[i];
    }
    float bx[4], by[4], bz[4];
    #pragma unroll
    for (int i = 0; i < 4; ++i){
      bx[i] = (wi & 4) ? ax[i+4] : ax[i];
      by[i] = (wi & 4) ? ay[i+4] : ay[i];
      bz[i] = (wi & 4) ? az[i+4] : az[i];
    }
    float cx[2], cy[2], cz[2];
    #pragma unroll
    for (int i = 0; i < 2; ++i){
      cx[i] = (wi & 2) ? bx[i+2] : bx[i];
      cy[i] = (wi & 2) ? by[i+2] : by[i];
      cz[i] = (wi & 2) ? bz[i+2] : bz[i];
    }
    float sx = (wi & 1) ? cx[1] : cx[0];
    float sy = (wi & 1) ? cy[1] : cy[0];
    float sz = (wi & 1) ? cz[1] : cz[0];
    px = __uint_as_float(__builtin_amdgcn_readlane(__float_as_uint(sx), wl));
    py = __uint_as_float(__builtin_amdgcn_readlane(__float_as_uint(sy), wl));
    pz = __uint_as_float(__builtin_amdgcn_readlane(__float_as_uint(sz), wl));
    if (t == 0){
      center[(size_t)(b*Gn+it)*3+0] = px;
      center[(size_t)(b*Gn+it)*3+1] = py;
      center[(size_t)(b*Gn+it)*3+2] = pz;
    }
  }
}

// ---------------------------------------------------------------- KNN
// key = (~dist_bits<<32)|(1023-n): max-reduce = min dist, tie -> lowest n.
__global__ __launch_bounds__(256) void knn_kernel(const float* __restrict__ pts,
                                                  const float* __restrict__ center,
                                                  float* __restrict__ nb){
  int gid = blockIdx.x; int b = gid >> 7;
  __shared__ float d2[1024];
  __shared__ float rv[4]; __shared__ int ri[4];
  int t = threadIdx.x;
  float cx = center[(size_t)gid*3+0], cy = center[(size_t)gid*3+1], cz = center[(size_t)gid*3+2];
  const float* p = pts + (size_t)b * Np * 3;
  for (int n = t; n < Np; n += 256){
    float dx = __fsub_rn(cx, p[n*3+0]);
    float dy = __fsub_rn(cy, p[n*3+1]);
    float dz = __fsub_rn(cz, p[n*3+2]);
    d2[n] = __fadd_rn(__fadd_rn(__fmul_rn(dx,dx), __fmul_rn(dy,dy)), __fmul_rn(dz,dz));
  }
  __syncthreads();
  for (int kk = 0; kk < Kn; ++kk){
    float v = 3e38f; int idx = 0;
    for (int n = t; n < Np; n += 256){
      float d = d2[n];
      if (d < v || (d == v && n < idx)){ v = d; idx = n; }
    }
    ull key = ((ull)(unsigned)(~__float_as_uint(v)) << 32) | (unsigned)(Np-1 - idx);
    key = redmax64(key);
    if ((t & 63) == 63){
      rv[t>>6] = __uint_as_float(~(unsigned)(key >> 32));
      ri[t>>6] = Np-1 - (int)(unsigned)(key & 0xFFFFFFFFu);
    }
    __syncthreads();
    if (t == 0){
      float bv = rv[0]; int bi = ri[0];
      for (int w = 1; w < 4; ++w){
        if (rv[w] < bv || (rv[w] == bv && ri[w] < bi)){ bv = rv[w]; bi = ri[w]; }
      }
      bi = min(max(bi, 0), Np-1);
      nb[((size_t)gid*Kn+kk)*3+0] = __fsub_rn(p[bi*3+0], cx);
      nb[((size_t)gid*Kn+kk)*3+1] = __fsub_rn(p[bi*3+1], cy);
      nb[((size_t)gid*Kn+kk)*3+2] = __fsub_rn(p[bi*3+2], cz);
      d2[bi] = 3e38f;
    }
    __syncthreads();
  }
}

// ---------------------------------------------------------------- MFMA GEMM
// C[M,N] = act(A[M,K](lda) @ W[N,K]^T + bias). bf16 MFMA, fp32 accumulate.
// GATE: A element = y[m,k] * silu(z[m,k]) with z at A col offset +768.
template<typename AT, int ACT, int GATE>
__global__ __launch_bounds__(256) void gemm_mfma(const AT* __restrict__ A, int lda,
                                                 const float* __restrict__ W,
                                                 const float* __restrict__ bias,
                                                 const float* __restrict__ g,
                                                 const float* __restrict__ bb,
                                                 float* __restrict__ C, int ldc,
                                                 int M, int N, int K){
  __shared__ __align__(16) short As[64*40];
  __shared__ __align__(16) short Ws[64*40];
  int bm = blockIdx.x * 64, bn = blockIdx.y * 64;
  int t = threadIdx.x;
  int row = t >> 2;
  int kseg = (t & 3) * 8;
  int w = t >> 6, lane = t & 63, m16 = lane & 15, q = lane >> 4;
  bool kvec = ((K & 3) == 0) && ((lda & 3) == 0 || sizeof(AT) == 2);
  floatx4 acc[4] = {};
  for (int k0 = 0; k0 < K; k0 += 32){
    if constexpr (GATE){
      const float* Ar = (const float*)A + (size_t)(bm + row)*lda + k0 + kseg;
      float4 y0 = *(const float4*)Ar;
      float4 y1 = *(const float4*)(Ar + 4);
      float4 z0 = *(const float4*)(Ar + 768);
      float4 z1 = *(const float4*)(Ar + 772);
      short* dst = &As[row*40 + kseg];
      dst[0] = f2bf(y0.x * (z0.x * fsig(z0.x)));
      dst[1] = f2bf(y0.y * (z0.y * fsig(z0.y)));
      dst[2] = f2bf(y0.z * (z0.z * fsig(z0.z)));
      dst[3] = f2bf(y0.w * (z0.w * fsig(z0.w)));
      dst[4] = f2bf(y1.x * (z1.x * fsig(z1.x)));
      dst[5] = f2bf(y1.y * (z1.y * fsig(z1.y)));
      dst[6] = f2bf(y1.z * (z1.z * fsig(z1.z)));
      dst[7] = f2bf(y1.w * (z1.w * fsig(z1.w)));
    } else if constexpr (sizeof(AT) == 2){
      *(short8*)&As[row*40 + kseg] =
          *(const short8*)((const short*)A + (size_t)(bm + row)*lda + k0 + kseg);
    } else {
      const float* Ar = (const float*)A + (size_t)(bm + row)*lda;
      short* dst = &As[row*40 + kseg];
      if (kvec && (k0 + kseg + 8 <= K)){
        float4 a0 = *(const float4*)(Ar + k0 + kseg);
        float4 a1 = *(const float4*)(Ar + k0 + kseg + 4);
        dst[0]=f2bf(a0.x); dst[1]=f2bf(a0.y); dst[2]=f2bf(a0.z); dst[3]=f2bf(a0.w);
        dst[4]=f2bf(a1.x); dst[5]=f2bf(a1.y); dst[6]=f2bf(a1.z); dst[7]=f2bf(a1.w);
      } else {
        #pragma unroll
        for (int j = 0; j < 8; ++j){
          int k = k0 + kseg + j;
          dst[j] = (k < K) ? f2bf(Ar[k]) : (short)0;
        }
      }
    }
    {
      int n = bn + row;
      short* dst = &Ws[row*40 + kseg];
      if (n < N && ((K & 3) == 0) && (k0 + kseg + 8 <= K)){
        const float* Wr = W + (size_t)n*K + k0 + kseg;
        float4 w0 = *(const float4*)Wr;
        float4 w1 = *(const float4*)(Wr + 4);
        dst[0]=f2bf(w0.x); dst[1]=f2bf(w0.y); dst[2]=f2bf(w0.z); dst[3]=f2bf(w0.w);
        dst[4]=f2bf(w1.x); dst[5]=f2bf(w1.y); dst[6]=f2bf(w1.z); dst[7]=f2bf(w1.w);
      } else {
        #pragma unroll
        for (int j = 0; j < 8; ++j){
          int k = k0 + kseg + j;
          dst[j] = (n < N && k < K) ? f2bf(W[(size_t)n*K + k]) : (short)0;
        }
      }
    }
    __syncthreads();
    short8 af = *(const short8*)&As[(w*16 + m16)*40 + q*8];
    #pragma unroll
    for (int j = 0; j < 4; ++j){
      short8 bfr = *(const short8*)&Ws[(j*16 + m16)*40 + q*8];
      acc[j] = __builtin_amdgcn_mfma_f32_16x16x32_bf16(af, bfr, acc[j], 0, 0, 0);
    }
    __syncthreads();
  }
  #pragma unroll
  for (int j = 0; j < 4; ++j){
    int n = bn + j*16 + m16;
    if (n < N){
      float bv = bias ? bias[n] : 0.f;
      float gv = 0.f, bbv = 0.f;
      if (ACT == 1){ gv = g[n] * BNS; bbv = bb[n]; }
      #pragma unroll
      for (int r = 0; r < 4; ++r){
        int m = bm + w*16 + q*4 + r;
        float v = acc[j][r] + bv;
        if (ACT == 1){ v = v * gv + bbv; v = fmaxf(v, 0.f); }
        C[(size_t)m*ldc + n] = v;
      }
    }
  }
}

// -------------------------------------------------- encoder max-pools
__global__ __launch_bounds__(256) void maxk_fg(float* __restrict__ f3in){
  int gg = blockIdx.x; int c = threadIdx.x;
  float m = -3e38f;
  for (int k = 0; k < Kn; ++k) m = fmaxf(m, f3in[((size_t)gg*Kn + k)*512 + 256 + c]);
  for (int k = 0; k < Kn; ++k) f3in[((size_t)gg*Kn + k)*512 + c] = m;
}

__global__ __launch_bounds__(384) void maxk_tok(const float* __restrict__ f4, float* __restrict__ tok){
  int gg = blockIdx.x; int c = threadIdx.x;
  float m = -3e38f;
  for (int k = 0; k < Kn; ++k) m = fmaxf(m, f4[((size_t)gg*Kn + k)*DM + c]);
  tok[(size_t)gg*DM + c] = m;
}

// -------------------------------------------------- pos embedding (adds into tok)
__global__ __launch_bounds__(128) void pos_kernel(const float* __restrict__ center,
                                                  const float* __restrict__ w1, const float* __restrict__ b1,
                                                  const float* __restrict__ w2, const float* __restrict__ b2,
                                                  float* __restrict__ tok){
  int gid = blockIdx.x;
  __shared__ float h1[128]; __shared__ float c3[3];
  int t = threadIdx.x;
  if (t < 3) c3[t] = center[(size_t)gid*3 + t];
  __syncthreads();
  float a = w1[t*3+0]*c3[0] + w1[t*3+1]*c3[1] + w1[t*3+2]*c3[2] + b1[t];
  h1[t] = 0.5f * a * (1.f + erff(a * 0.70710678118654752440f));
  __syncthreads();
  for (int c = t; c < DM; c += 128){
    float s = b2[c];
    for (int j = 0; j < 128; ++j) s += w2[(size_t)c*128 + j] * h1[j];
    tok[(size_t)gid*DM + c] += s;
  }
}

// -------------------------------------------------- stable argsort (rank count)
__global__ __launch_bounds__(128) void sort_kernel(const float* __restrict__ center,
                                                   int* __restrict__ order){
  int bax = blockIdx.x; int b = bax / 3, ax = bax % 3;
  __shared__ float key[128];
  int t = threadIdx.x;
  key[t] = center[(size_t)(b*Gn + t)*3 + ax];
  __syncthreads();
  float kt = key[t]; int r = 0;
  for (int j = 0; j < Gn; ++j){
    float kj = key[j];
    r += (kj < kt || (kj == kt && j < t)) ? 1 : 0;
  }
  r = min(max(r, 0), Gn-1);
  order[b*Ln + ax*Gn + r] = t;
}

// -------------------------------------------------- token gather + res init
__global__ __launch_bounds__(256) void build_h(const float* __restrict__ tok,
                        const int* __restrict__ order,
                        float* __restrict__ h, float* __restrict__ res){
  int i = blockIdx.x * blockDim.x + threadIdx.x;
  if (i >= Bn*Ln*DM) return;
  int c = i % DM; int l = (i / DM) % Ln; int b = i / (DM*Ln);
  int src = order[b*Ln + l];
  src = min(max(src, 0), Gn-1);
  h[i] = tok[((size_t)(b*Gn + src))*DM + c];
  res[i] = 0.f;
}

// -------------------------------------------------- res += h; x = LN(res)*w+b (bf16 out)
__global__ __launch_bounds__(256) void ln_res_kernel(const float* __restrict__ h,
                                                     float* __restrict__ res,
                                                     bf16* __restrict__ x,
                                                     const float* __restrict__ w,
                                                     const float* __restrict__ bias){
  int wv = threadIdx.x >> 6, ln = threadIdx.x & 63;
  int tokid = blockIdx.x*4 + wv;
  const float* hr = h + (size_t)tokid*DM;
  float* rr = res + (size_t)tokid*DM;
  bf16* xr = x + (size_t)tokid*DM;
  float v[6]; float s = 0.f;
  #pragma unroll
  for (int i = 0; i < 6; ++i){ int c = ln + 64*i; float t = hr[c] + rr[c]; rr[c] = t; v[i] = t; s += t; }
  #pragma unroll
  for (int o = 32; o > 0; o >>= 1) s += __shfl_xor(s, o);
  float mu = s * (1.f/DM);
  float q = 0.f;
  #pragma unroll
  for (int i = 0; i < 6; ++i){ float d = v[i] - mu; q += d*d; }
  #pragma unroll
  for (int o = 32; o > 0; o >>= 1) q += __shfl_xor(q, o);
  float rstd = rsqrtf(q * (1.f/DM) + EPSf);
  #pragma unroll
  for (int i = 0; i < 6; ++i){ int c = ln + 64*i;
    xr[c] = __float2bfloat16((v[i]-mu)*rstd*w[c] + bias[c]); }
}

// -------------------------------------------------- conv (big path): xz -> ucv, one dispatch
__global__ __launch_bounds__(256) void conv_fused(const float* __restrict__ xz,
                                                  float* __restrict__ ucv,
                                                  const float* __restrict__ cw,
                                                  const float* __restrict__ cb){
  int blk = blockIdx.x;
  int lc = blk % NLC; int bd = blk / NLC; int dch = bd % 3; int b = bd / 3;
  int t = threadIdx.x; int d = dch*256 + t;
  int l0 = lc*16;
  float w0 = cw[d*4+0], w1 = cw[d*4+1], w2 = cw[d*4+2], w3 = cw[d*4+3];
  float bias = cb[d];
  float u0 = (l0 >= 3) ? xz[((size_t)(b*Ln + l0-3))*1536 + d] : 0.f;
  float u1 = (l0 >= 2) ? xz[((size_t)(b*Ln + l0-2))*1536 + d] : 0.f;
  float u2 = (l0 >= 1) ? xz[((size_t)(b*Ln + l0-1))*1536 + d] : 0.f;
  const float* pin = xz + ((size_t)(b*Ln + l0))*1536 + d;
  float* pout = ucv + ((size_t)(b*Ln + l0))*DI + d;
  float r[16];
  #pragma unroll
  for (int i = 0; i < 16; ++i) r[i] = pin[(size_t)i*1536];
  #pragma unroll
  for (int i = 0; i < 16; ++i){
    float v = u0*w0 + u1*w1 + u2*w2 + r[i]*w3 + bias;
    pout[(size_t)i*DI] = v * fsig(v);
    u0 = u1; u1 = u2; u2 = r[i];
  }
}

// -------------------------------------------------- conv (small path): 2-pass in place
__global__ __launch_bounds__(256) void conv_save(const float* __restrict__ xz,
                                                 float* __restrict__ bnd){
  int blk = blockIdx.x;
  int lc = blk % NLC; int bd = blk / NLC; int dch = bd % 3; int b = bd / 3;
  int t = threadIdx.x; int d = dch*256 + t;
  int l0 = lc*16;
  #pragma unroll
  for (int j = 0; j < 3; ++j){
    int l = l0 - 3 + j;
    float v = (l >= 0) ? xz[((size_t)(b*Ln + l))*1536 + d] : 0.f;
    bnd[(((size_t)blk)*3 + j)*256 + t] = v;
  }
}

__global__ __launch_bounds__(256) void conv_apply(float* __restrict__ xz,
                                                  const float* __restrict__ bnd,
                                                  const float* __restrict__ cw,
                                                  const float* __restrict__ cb){
  int blk = blockIdx.x;
  int lc = blk % NLC; int bd = blk / NLC; int dch = bd % 3; int b = bd / 3;
  int t = threadIdx.x; int d = dch*256 + t;
  int l0 = lc*16;
  float w0 = cw[d*4+0], w1 = cw[d*4+1], w2 = cw[d*4+2], w3 = cw[d*4+3];
  float bias = cb[d];
  float u0 = bnd[(((size_t)blk)*3 + 0)*256 + t];
  float u1 = bnd[(((size_t)blk)*3 + 1)*256 + t];
  float u2 = bnd[(((size_t)blk)*3 + 2)*256 + t];
  float* p = xz + ((size_t)(b*Ln + l0))*1536 + d;
  float r[16];
  #pragma unroll
  for (int i = 0; i < 16; ++i) r[i] = p[(size_t)i*1536];
  #pragma unroll
  for (int i = 0; i < 16; ++i){
    float v = u0*w0 + u1*w1 + u2*w2 + r[i]*w3 + bias;
    p[(size_t)i*1536] = v * fsig(v);
    u0 = u1; u1 = u2; u2 = r[i];
  }
}

// -------------------------------------------------- chunked selective scan
// Phase A: per (b,dch,chunk) block, local scan from h=0 -> S[16], sum dt.
__global__ __launch_bounds__(256) void scanA_kernel(const float* __restrict__ usrc, int uld,
                                                    const float* __restrict__ xdb,
                                                    const float* __restrict__ dpw,
                                                    const float* __restrict__ dpb,
                                                    const float* __restrict__ A_log,
                                                    float* __restrict__ SB_S,
                                                    float* __restrict__ SB_dt){
  __shared__ float sRow[CHS*56];
  __shared__ float sU[CHS*256];
  int blk = blockIdx.x;
  int c = blk % NCH; int bd = blk / NCH; int dch = bd % 3; int b = bd / 3;
  int t = threadIdx.x; int d = dch*256 + t;
  int l0 = c*CHS;
  for (int i = t; i < CHS*56; i += 256) sRow[i] = xdb[((size_t)(b*Ln + l0))*56 + i];
  const float* up = usrc + ((size_t)(b*Ln + l0))*uld + dch*256;
  #pragma unroll
  for (int i = 0; i < CHS; ++i) sU[i*256 + t] = up[(size_t)i*uld + t];
  float w[DTR];
  const float* wp = dpw + (size_t)d*DTR;
  #pragma unroll
  for (int j = 0; j < DTR; ++j) w[j] = wp[j];
  float a2[DSt], h[DSt];
  const float* ap = A_log + (size_t)d*DSt;
  #pragma unroll
  for (int s = 0; s < DSt; ++s){ a2[s] = -__expf(ap[s]) * LOG2E; h[s] = 0.f; }
  float dbias = dpb[d];
  float sumdt = 0.f;
  __syncthreads();
  for (int i = 0; i < CHS; ++i){
    int ro = i*56;
    float dtr = dbias;
    #pragma unroll
    for (int j = 0; j < DTR; ++j) dtr += w[j] * sRow[ro + j];
    float dtv = fsoftplus(dtr);
    sumdt += dtv;
    float du = dtv * sU[i*256 + t];
    #pragma unroll
    for (int s = 0; s < DSt; ++s)
      h[s] = exp2f(dtv * a2[s]) * h[s] + du * sRow[ro + 24 + s];
  }
  size_t sb = ((size_t)blk*256 + t)*16;
  #pragma unroll
  for (int s = 0; s < DSt; ++s) SB_S[sb + s] = h[s];
  SB_dt[(size_t)blk*256 + t] = sumdt;
}

// Phase B (combine fused): prefix h_in over earlier chunks, re-run chunk,
// write UNGATED y into xz u-half (gate applied in out_proj staging).
__global__ __launch_bounds__(256) void scanB_kernel(float* __restrict__ xz,
                                                    const float* __restrict__ usrc, int uld,
                                                    const float* __restrict__ xdb,
                                                    const float* __restrict__ dpw,
                                                    const float* __restrict__ dpb,
                                                    const float* __restrict__ A_log,
                                                    const float* __restrict__ Dp,
                                                    const float* __restrict__ SB_S,
                                                    const float* __restrict__ SB_dt){
  __shared__ float sRow[CHS*56];
  __shared__ float sU[CHS*256];
  int blk = blockIdx.x;
  int c = blk % NCH; int bd = blk / NCH; int dch = bd % 3; int b = bd / 3;
  int t = threadIdx.x; int d = dch*256 + t;
  int l0 = c*CHS;
  for (int i = t; i < CHS*56; i += 256) sRow[i] = xdb[((size_t)(b*Ln + l0))*56 + i];
  const float* up = usrc + ((size_t)(b*Ln + l0))*uld + dch*256;
  #pragma unroll
  for (int i = 0; i < CHS; ++i) sU[i*256 + t] = up[(size_t)i*uld + t];
  float w[DTR];
  const float* wp = dpw + (size_t)d*DTR;
  #pragma unroll
  for (int j = 0; j < DTR; ++j) w[j] = wp[j];
  float a2[DSt], h[DSt];
  const float* ap = A_log + (size_t)d*DSt;
  #pragma unroll
  for (int s = 0; s < DSt; ++s){ a2[s] = -__expf(ap[s]) * LOG2E; h[s] = 0.f; }
  for (int cc = 0; cc < c; ++cc){
    size_t base = (((size_t)bd*NCH + cc)*256 + t)*16;
    float sd = SB_dt[((size_t)bd*NCH + cc)*256 + t];
    #pragma unroll
    for (int s = 0; s < DSt; ++s)
      h[s] = exp2f(sd * a2[s]) * h[s] + SB_S[base + s];
  }
  float dbias = dpb[d];
  float Dd = Dp[d];
  float* ydst = xz + ((size_t)(b*Ln + l0))*1536 + dch*256;
  __syncthreads();
  for (int i = 0; i < CHS; ++i){
    int ro = i*56;
    float dtr = dbias;
    #pragma unroll
    for (int j = 0; j < DTR; ++j) dtr += w[j] * sRow[ro + j];
    float dtv = fsoftplus(dtr);
    float u = sU[i*256 + t];
    float du = dtv * u;
    float yv = 0.f;
    #pragma unroll
    for (int s = 0; s < DSt; ++s){
      h[s] = exp2f(dtv * a2[s]) * h[s] + du * sRow[ro + 24 + s];
      yv += h[s] * sRow[ro + 40 + s];
    }
    ydst[(size_t)i*1536 + t] = yv + u*Dd;
  }
}

// -------------------------------------------------- final two LayerNorms
__global__ __launch_bounds__(256) void final_ln_kernel(const float* __restrict__ h,
                                                       const float* __restrict__ res,
                                                       const float* w1, const float* b1,
                                                       const float* w2, const float* b2,
                                                       float* __restrict__ x){
  int wv = threadIdx.x >> 6, ln = threadIdx.x & 63;
  int tokid = blockIdx.x*4 + wv;
  const float* hr = h + (size_t)tokid*DM;
  const float* rr = res + (size_t)tokid*DM;
  float* xr = x + (size_t)tokid*DM;
  float v[6]; float s = 0.f;
  #pragma unroll
  for (int i = 0; i < 6; ++i){ int c = ln + 64*i; v[i] = hr[c] + rr[c]; s += v[i]; }
  #pragma unroll
  for (int o = 32; o > 0; o >>= 1) s += __shfl_xor(s, o);
  float mu = s * (1.f/DM); float q = 0.f;
  #pragma unroll
  for (int i = 0; i < 6; ++i){ float dd = v[i]-mu; q += dd*dd; }
  #pragma unroll
  for (int o = 32; o > 0; o >>= 1) q += __shfl_xor(q, o);
  float rstd = rsqrtf(q * (1.f/DM) + EPSf);
  float u[6]; float s2 = 0.f;
  #pragma unroll
  for (int i = 0; i < 6; ++i){ int c = ln + 64*i; u[i] = (v[i]-mu)*rstd*w1[c] + b1[c]; s2 += u[i]; }
  #pragma unroll
  for (int o = 32; o > 0; o >>= 1) s2 += __shfl_xor(s2, o);
  float mu2 = s2 * (1.f/DM); float q2 = 0.f;
  #pragma unroll
  for (int i = 0; i < 6; ++i){ float dd = u[i]-mu2; q2 += dd*dd; }
  #pragma unroll
  for (int o = 32; o > 0; o >>= 1) q2 += __shfl_xor(q2, o);
  float rstd2 = rsqrtf(q2 * (1.f/DM) + EPSf);
  #pragma unroll
  for (int i = 0; i < 6; ++i){ int c = ln + 64*i; xr[c] = (u[i]-mu2)*rstd2*w2[c] + b2[c]; }
}

// -------------------------------------------------- mean over L + MLP head
__global__ __launch_bounds__(384) void head_kernel(const float* __restrict__ x,
    const float* w1, const float* b1, const float* g1, const float* bb1,
    const float* w2, const float* b2, const float* g2, const float* bb2,
    const float* w3, const float* b3, float* __restrict__ out){
  int b = blockIdx.x; int t = threadIdx.x;
  __shared__ float feat[DM]; __shared__ float h1[256]; __shared__ float h2[256];
  float s = 0.f;
  for (int l = 0; l < Ln; ++l) s += x[((size_t)(b*Ln + l))*DM + t];
  feat[t] = s * (1.f/Ln);
  __syncthreads();
  if (t < 256){
    float a = b1[t];
    for (int j = 0; j < DM; ++j) a += w1[(size_t)t*DM + j] * feat[j];
    a = a * (g1[t] * BNS) + bb1[t];
    h1[t] = fmaxf(a, 0.f);
  }
  __syncthreads();
  if (t < 256){
    float a = b2[t];
    for (int j = 0; j < 256; ++j) a += w2[(size_t)t*256 + j] * h1[j];
    a = a * (g2[t] * BNS) + bb2[t];
    h2[t] = fmaxf(a, 0.f);
  }
  __syncthreads();
  if (t < CLSn){
    float a = b3[t];
    for (int j = 0; j < 256; ++j) a += w3[(size_t)t*256 + j] * h2[j];
    out[b*CLSn + t] = a;
  }
}

extern "C" void kernel_launch(void* const* d_in, const int* in_sizes, int n_in,
                              void* d_out, int out_size, void* d_ws, size_t ws_size,
                              hipStream_t stream) {
  if (n_in < 42) return;
  if (out_size < Bn*CLSn) return;
  constexpr size_t WS_FLOATS = 3919936;
  if (ws_size < WS_FLOATS * sizeof(float)) return;
  constexpr size_t BIG_BASE = 3919936;
  constexpr size_t BIG_FLOATS = 8388608 + 8388608 + 2097152; // F3in,F3,F1 (F4/ucv alias F3in)
  const bool big = ws_size >= (BIG_BASE + BIG_FLOATS) * sizeof(float);

  const float* pts       = (const float*)d_in[0];
  const float* enc_w1    = (const float*)d_in[1];  const float* enc_b1    = (const float*)d_in[2];
  const float* enc_bn1_g = (const float*)d_in[3];  const float* enc_bn1_b = (const float*)d_in[4];
  const float* enc_w2    = (const float*)d_in[5];  const float* enc_b2    = (const float*)d_in[6];
  const float* enc_w3    = (const float*)d_in[7];  const float* enc_b3    = (const float*)d_in[8];
  const float* enc_bn2_g = (const float*)d_in[9];  const float* enc_bn2_b = (const float*)d_in[10];
  const float* enc_w4    = (const float*)d_in[11]; const float* enc_b4    = (const float*)d_in[12];
  const float* pos_w1    = (const float*)d_in[13]; const float* pos_b1    = (const float*)d_in[14];
  const float* pos_w2    = (const float*)d_in[15]; const float* pos_b2    = (const float*)d_in[16];
  const float* ln_w      = (const float*)d_in[17]; const float* ln_b      = (const float*)d_in[18];
  const float* in_proj_w = (const float*)d_in[19];
  const float* conv_w    = (const float*)d_in[20]; const float* conv_b    = (const float*)d_in[21];
  const float* x_proj_w  = (const float*)d_in[22];
  const float* dt_proj_w = (const float*)d_in[23]; const float* dt_proj_b = (const float*)d_in[24];
  const float* A_log     = (const float*)d_in[25]; const float* D_param   = (const float*)d_in[26];
  const float* out_proj_w= (const float*)d_in[27];
  const float* normf_w   = (const float*)d_in[28]; const float* normf_b   = (const float*)d_in[29];
  const float* norm_w    = (const float*)d_in[30]; const float* norm_b    = (const float*)d_in[31];
  const float* head_w1   = (const float*)d_in[32]; const float* head_b1   = (const float*)d_in[33];
  const float* head_bn1_g= (const float*)d_in[34]; const float* head_bn1_b= (const float*)d_in[35];
  const float* head_w2   = (const float*)d_in[36]; const float* head_b2   = (const float*)d_in[37];
  const float* head_bn2_g= (const float*)d_in[38]; const float* head_bn2_b= (const float*)d_in[39];
  const float* head_w3   = (const float*)d_in[40]; const float* head_b3   = (const float*)d_in[41];

  float* ws = (float*)d_ws;
  float* hb   = ws;                   // 589,824 floats
  float* resb = ws + 589824;          // 589,824
  float* U    = ws + 1179648;         // 2,740,224
  // setup/encoder view of U
  float* center = U;
  float* nb     = U + 1536;
  float* tok    = U + 50688;
  int*   order  = (int*)(U + 247296);
  float* eb0    = U + 262144;
  float* eb1    = U + 1310720;
  // mamba view of U
  float* xz   = U;                      // 2,359,296 (1536 x 1536)
  float* xdb  = U + 2359296;            // 86,016
  bf16*  xb   = (bf16*)(U + 2445312);   // 589,824 bf16 in 294,912 float slots
  float* SBdt = U + 2445312;            // 36,864 (xb dead when scanA runs)
  float* BND  = U + 2482176;            // 221,184
  float* SBS  = hb;                     // 589,824 (hb dead between ln_res and out_proj)
  float* xf   = U;
  // big-path buffers (beyond base region)
  float* F3in = ws + BIG_BASE;          // 8,388,608 (16384 x 512)
  float* F3   = ws + BIG_BASE + 8388608;
  float* F1   = ws + BIG_BASE + 16777216;
  float* F4   = F3in;
  float* ucv  = F3in;                   // 1,179,648 (1536 x 768) — encoder phase done

  fps_kernel<<<Bn, 64, 0, stream>>>(pts, center);
  knn_kernel<<<Bn*Gn, 256, 0, stream>>>(pts, center, nb);

  if (big){
    gemm_mfma<float,1,0><<<dim3(256,2), 256, 0, stream>>>(nb, 3, enc_w1, enc_b1,
        enc_bn1_g, enc_bn1_b, F1, 128, 16384, 128, 3);
    gemm_mfma<float,0,0><<<dim3(256,4), 256, 0, stream>>>(F1, 128, enc_w2, enc_b2,
        nullptr, nullptr, F3in + 256, 512, 16384, 256, 128);
    maxk_fg<<<512, 256, 0, stream>>>(F3in);
    gemm_mfma<float,1,0><<<dim3(256,8), 256, 0, stream>>>(F3in, 512, enc_w3, enc_b3,
        enc_bn2_g, enc_bn2_b, F3, 512, 16384, 512, 512);
    gemm_mfma<float,0,0><<<dim3(256,6), 256, 0, stream>>>(F3, 512, enc_w4, enc_b4,
        nullptr, nullptr, F4, 384, 16384, 384, 512);
    maxk_tok<<<512, 384, 0, stream>>>(F4, tok);
  } else {
    for (int ch = 0; ch < 8; ++ch){
      const float* nb_c = nb + (size_t)ch*2048*3;
      float* tok_c = tok + (size_t)ch*64*DM;
      gemm_mfma<float,1,0><<<dim3(32,2), 256, 0, stream>>>(nb_c, 3, enc_w1, enc_b1,
          enc_bn1_g, enc_bn1_b, eb1, 128, 2048, 128, 3);
      gemm_mfma<float,0,0><<<dim3(32,4), 256, 0, stream>>>(eb1, 128, enc_w2, enc_b2,
          nullptr, nullptr, eb0 + 256, 512, 2048, 256, 128);
      maxk_fg<<<64, 256, 0, stream>>>(eb0);
      gemm_mfma<float,1,0><<<dim3(32,8), 256, 0, stream>>>(eb0, 512, enc_w3, enc_b3,
          enc_bn2_g, enc_bn2_b, eb1, 512, 2048, 512, 512);
      gemm_mfma<float,0,0><<<dim3(32,6), 256, 0, stream>>>(eb1, 512, enc_w4, enc_b4,
          nullptr, nullptr, eb0, 384, 2048, 384, 512);
      maxk_tok<<<64, 384, 0, stream>>>(eb0, tok_c);
    }
  }

  pos_kernel<<<Bn*Gn, 128, 0, stream>>>(center, pos_w1, pos_b1, pos_w2, pos_b2, tok);
  sort_kernel<<<Bn*3, 128, 0, stream>>>(center, order);
  build_h<<<(Bn*Ln*DM + 255)/256, 256, 0, stream>>>(tok, order, hb, resb);

  for (int l = 0; l < DEPTH; ++l){
    const float* lnw  = ln_w      + (size_t)l*DM;
    const float* lnb  = ln_b      + (size_t)l*DM;
    const float* ipw  = in_proj_w + (size_t)l*1536*DM;
    const float* cw   = conv_w    + (size_t)l*DI*4;
    const float* cb   = conv_b    + (size_t)l*DI;
    const float* xpw  = x_proj_w  + (size_t)l*56*DI;
    const float* dpw  = dt_proj_w + (size_t)l*DI*DTR;
    const float* dpb  = dt_proj_b + (size_t)l*DI;
    const float* Alg  = A_log     + (size_t)l*DI*DSt;
    const float* Dpar = D_param   + (size_t)l*DI;
    const float* opw  = out_proj_w+ (size_t)l*DM*DI;

    ln_res_kernel<<<Bn*Ln/4, 256, 0, stream>>>(hb, resb, xb, lnw, lnb);
    gemm_mfma<bf16,0,0><<<dim3(24,24), 256, 0, stream>>>(xb, DM, ipw,
        nullptr, nullptr, nullptr, xz, 1536, Bn*Ln, 1536, DM);
    if (big){
      conv_fused<<<Bn*3*NLC, 256, 0, stream>>>(xz, ucv, cw, cb);
      gemm_mfma<float,0,0><<<dim3(24,1), 256, 0, stream>>>(ucv, DI, xpw,
          nullptr, nullptr, nullptr, xdb, 56, Bn*Ln, 56, DI);
      scanA_kernel<<<Bn*3*NCH, 256, 0, stream>>>(ucv, DI, xdb, dpw, dpb, Alg, SBS, SBdt);
      scanB_kernel<<<Bn*3*NCH, 256, 0, stream>>>(xz, ucv, DI, xdb, dpw, dpb, Alg, Dpar, SBS, SBdt);
    } else {
      conv_save<<<Bn*3*NLC, 256, 0, stream>>>(xz, BND);
      conv_apply<<<Bn*3*NLC, 256, 0, stream>>>(xz, BND, cw, cb);
      gemm_mfma<float,0,0><<<dim3(24,1), 256, 0, stream>>>(xz, 1536, xpw,
          nullptr, nullptr, nullptr, xdb, 56, Bn*Ln, 56, DI);
      scanA_kernel<<<Bn*3*NCH, 256, 0, stream>>>(xz, 1536, xdb, dpw, dpb, Alg, SBS, SBdt);
      scanB_kernel<<<Bn*3*NCH, 256, 0, stream>>>(xz, xz, 1536, xdb, dpw, dpb, Alg, Dpar, SBS, SBdt);
    }
    gemm_mfma<float,0,1><<<dim3(24,6), 256, 0, stream>>>(xz, 1536, opw,
        nullptr, nullptr, nullptr, hb, DM, Bn*Ln, DM, DI);
  }

  final_ln_kernel<<<Bn*Ln/4, 256, 0, stream>>>(hb, resb, normf_w, normf_b, norm_w, norm_b, xf);
  head_kernel<<<Bn, 384, 0, stream>>>(xf, head_w1, head_b1, head_bn1_g, head_bn1_b,
                                      head_w2, head_b2, head_bn2_g, head_bn2_b,
                                      head_w3, head_b3, (float*)d_out);
}

// Round 10
// 1785.776 us; speedup vs baseline: 3.7440x; 1.1405x over previous
//
#include <hip/hip_runtime.h>
#include <hip/hip_bf16.h>

using bf16 = __hip_bfloat16;
using short8  = __attribute__((ext_vector_type(8))) short;
using floatx4 = __attribute__((ext_vector_type(4))) float;
using ull = unsigned long long;

constexpr int Bn = 4, Np = 1024, Gn = 128, Kn = 32;
constexpr int DM = 384, DEPTH = 12, CLSn = 40;
constexpr int DI = 768, DSt = 16, DTR = 24;
constexpr int Ln = 384;
constexpr int NCH = 12, CHS = 32;      // scan: 12 chunks x 32 steps
constexpr int NLC = 24;                // conv: 24 chunks x 16 steps
constexpr float EPSf = 1e-5f;
constexpr float BNS = 0.99999500003749968752f; // 1/sqrt(1+1e-5)
constexpr float LOG2E = 1.4426950408889634f;

static __device__ __forceinline__ short f2bf(float f){
  bf16 h = __float2bfloat16(f);
  return *reinterpret_cast<short*>(&h);
}
static __device__ __forceinline__ float fsig(float x){ return 1.f/(1.f + __expf(-x)); }
static __device__ __forceinline__ float fsoftplus(float x){
  return fmaxf(x, 0.f) + __logf(1.f + __expf(-fabsf(x)));
}

// DPP lane move (VALU-latency, no LDS). bound_ctrl=true -> invalid lanes read 0.
template<int CTRL>
static __device__ __forceinline__ int dppmov(int x){
  return __builtin_amdgcn_update_dpp(0, x, CTRL, 0xF, 0xF, true);
}
// 64-bit unsigned max reduce to lane 63 via DPP (row_shr 1/2/4/8, bcast15, bcast31).
static __device__ __forceinline__ ull redmax64(ull key){
  #define RSTEP(CTRL) { \
    int hi = (int)(unsigned)(key >> 32), lo = (int)(unsigned)key; \
    int h2 = dppmov<CTRL>(hi), l2 = dppmov<CTRL>(lo); \
    ull k2 = ((ull)(unsigned)h2 << 32) | (unsigned)l2; \
    if (k2 > key) key = k2; }
  RSTEP(0x111) RSTEP(0x112) RSTEP(0x114) RSTEP(0x118) RSTEP(0x142) RSTEP(0x143)
  #undef RSTEP
  return key;  // lane 63 holds the wave max
}

// ---------------------------------------------------------------- FPS
// Single wave. Points in LDS (lane reads t+64i: conflict-free), dmin in regs,
// DPP 64-bit max-reduce, winner coords via wave-uniform LDS broadcast read.
// key = (dist_bits<<32)|(1023-n): argmax with tie -> lowest n (np.argmax).
__global__ __launch_bounds__(64) void fps_kernel(const float* __restrict__ pts,
                                                 float* __restrict__ center){
  int b = blockIdx.x, t = threadIdx.x;
  __shared__ float xs[1024], ys[1024], zs[1024];
  const float* p = pts + (size_t)b * Np * 3;
  float D[16];
  #pragma unroll
  for (int i = 0; i < 16; ++i){
    int n = t + 64*i;
    xs[n] = p[n*3+0]; ys[n] = p[n*3+1]; zs[n] = p[n*3+2];
    D[i] = 1e10f;
  }
  float px = xs[0], py = ys[0], pz = zs[0];   // uniform addr -> broadcast
  if (t == 0){
    center[(size_t)(b*Gn)*3+0] = px;
    center[(size_t)(b*Gn)*3+1] = py;
    center[(size_t)(b*Gn)*3+2] = pz;
  }
  for (int it = 1; it < Gn; ++it){
    float v = -1.f; int nbest = t;
    #pragma unroll
    for (int i = 0; i < 16; ++i){
      int n = t + 64*i;
      float dx = __fsub_rn(xs[n], px);
      float dy = __fsub_rn(ys[n], py);
      float dz = __fsub_rn(zs[n], pz);
      float d  = __fadd_rn(__fadd_rn(__fmul_rn(dx,dx), __fmul_rn(dy,dy)), __fmul_rn(dz,dz));
      float dm = fminf(D[i], d); D[i] = dm;
      if (dm > v){ v = dm; nbest = n; }   // ascending n: lowest n on tie
    }
    ull key = ((ull)__float_as_uint(v) << 32) | (unsigned)(Np-1 - nbest);
    key = redmax64(key);
    int lo63 = __builtin_amdgcn_readlane((int)(unsigned)(key & 0xFFFFFFFFu), 63);
    int wn = Np-1 - lo63;
    wn = min(max(wn, 0), Np-1);           // wave-uniform (SGPR)
    px = xs[wn]; py = ys[wn]; pz = zs[wn]; // broadcast reads
    if (t == 0){
      center[(size_t)(b*Gn+it)*3+0] = px;
      center[(size_t)(b*Gn+it)*3+1] = py;
      center[(size_t)(b*Gn+it)*3+2] = pz;
    }
  }
}

// ---------------------------------------------------------------- KNN
// key = (~dist_bits<<32)|(1023-n): max-reduce = min dist, tie -> lowest n.
__global__ __launch_bounds__(256) void knn_kernel(const float* __restrict__ pts,
                                                  const float* __restrict__ center,
                                                  float* __restrict__ nb){
  int gid = blockIdx.x; int b = gid >> 7;
  __shared__ float d2[1024];
  __shared__ float rv[4]; __shared__ int ri[4];
  int t = threadIdx.x;
  float cx = center[(size_t)gid*3+0], cy = center[(size_t)gid*3+1], cz = center[(size_t)gid*3+2];
  const float* p = pts + (size_t)b * Np * 3;
  for (int n = t; n < Np; n += 256){
    float dx = __fsub_rn(cx, p[n*3+0]);
    float dy = __fsub_rn(cy, p[n*3+1]);
    float dz = __fsub_rn(cz, p[n*3+2]);
    d2[n] = __fadd_rn(__fadd_rn(__fmul_rn(dx,dx), __fmul_rn(dy,dy)), __fmul_rn(dz,dz));
  }
  __syncthreads();
  for (int kk = 0; kk < Kn; ++kk){
    float v = 3e38f; int idx = 0;
    for (int n = t; n < Np; n += 256){
      float d = d2[n];
      if (d < v || (d == v && n < idx)){ v = d; idx = n; }
    }
    ull key = ((ull)(unsigned)(~__float_as_uint(v)) << 32) | (unsigned)(Np-1 - idx);
    key = redmax64(key);
    if ((t & 63) == 63){
      rv[t>>6] = __uint_as_float(~(unsigned)(key >> 32));
      ri[t>>6] = Np-1 - (int)(unsigned)(key & 0xFFFFFFFFu);
    }
    __syncthreads();
    if (t == 0){
      float bv = rv[0]; int bi = ri[0];
      for (int w = 1; w < 4; ++w){
        if (rv[w] < bv || (rv[w] == bv && ri[w] < bi)){ bv = rv[w]; bi = ri[w]; }
      }
      bi = min(max(bi, 0), Np-1);
      nb[((size_t)gid*Kn+kk)*3+0] = __fsub_rn(p[bi*3+0], cx);
      nb[((size_t)gid*Kn+kk)*3+1] = __fsub_rn(p[bi*3+1], cy);
      nb[((size_t)gid*Kn+kk)*3+2] = __fsub_rn(p[bi*3+2], cz);
      d2[bi] = 3e38f;
    }
    __syncthreads();
  }
}

// ---------------------------------------------------------------- fp32 -> bf16 convert
__global__ __launch_bounds__(256) void cvt_bf16(const float* __restrict__ s,
                                                bf16* __restrict__ d, int n){
  int i = (blockIdx.x*256 + threadIdx.x)*4;
  if (i < n){
    float4 v = *(const float4*)(s + i);
    short* o = (short*)d + i;
    o[0] = f2bf(v.x); o[1] = f2bf(v.y); o[2] = f2bf(v.z); o[3] = f2bf(v.w);
  }
}

// ---------------------------------------------------------------- MFMA GEMM
// C[M,N] = act(A[M,K](lda) @ W[N,K]^T + bias). bf16 MFMA, fp32 accumulate.
// WT = float (convert on the fly) or bf16 (preconverted; requires K%32==0).
// GATE: A element = y[m,k] * silu(z[m,k]) with z at A col offset +768.
template<typename AT, typename WT, int ACT, int GATE>
__global__ __launch_bounds__(256) void gemm_mfma(const AT* __restrict__ A, int lda,
                                                 const WT* __restrict__ W,
                                                 const float* __restrict__ bias,
                                                 const float* __restrict__ g,
                                                 const float* __restrict__ bb,
                                                 float* __restrict__ C, int ldc,
                                                 int M, int N, int K){
  __shared__ __align__(16) short As[64*40];
  __shared__ __align__(16) short Ws[64*40];
  int bm = blockIdx.x * 64, bn = blockIdx.y * 64;
  int t = threadIdx.x;
  int row = t >> 2;
  int kseg = (t & 3) * 8;
  int w = t >> 6, lane = t & 63, m16 = lane & 15, q = lane >> 4;
  bool kvec = ((K & 3) == 0) && ((lda & 3) == 0 || sizeof(AT) == 2);
  floatx4 acc[4] = {};
  for (int k0 = 0; k0 < K; k0 += 32){
    // ---- A staging
    if constexpr (GATE){
      const float* Ar = (const float*)A + (size_t)(bm + row)*lda + k0 + kseg;
      float4 y0 = *(const float4*)Ar;
      float4 y1 = *(const float4*)(Ar + 4);
      float4 z0 = *(const float4*)(Ar + 768);
      float4 z1 = *(const float4*)(Ar + 772);
      short* dst = &As[row*40 + kseg];
      dst[0] = f2bf(y0.x * (z0.x * fsig(z0.x)));
      dst[1] = f2bf(y0.y * (z0.y * fsig(z0.y)));
      dst[2] = f2bf(y0.z * (z0.z * fsig(z0.z)));
      dst[3] = f2bf(y0.w * (z0.w * fsig(z0.w)));
      dst[4] = f2bf(y1.x * (z1.x * fsig(z1.x)));
      dst[5] = f2bf(y1.y * (z1.y * fsig(z1.y)));
      dst[6] = f2bf(y1.z * (z1.z * fsig(z1.z)));
      dst[7] = f2bf(y1.w * (z1.w * fsig(z1.w)));
    } else if constexpr (sizeof(AT) == 2){
      *(short8*)&As[row*40 + kseg] =
          *(const short8*)((const short*)A + (size_t)(bm + row)*lda + k0 + kseg);
    } else {
      const float* Ar = (const float*)A + (size_t)(bm + row)*lda;
      short* dst = &As[row*40 + kseg];
      if (kvec && (k0 + kseg + 8 <= K)){
        float4 a0 = *(const float4*)(Ar + k0 + kseg);
        float4 a1 = *(const float4*)(Ar + k0 + kseg + 4);
        dst[0]=f2bf(a0.x); dst[1]=f2bf(a0.y); dst[2]=f2bf(a0.z); dst[3]=f2bf(a0.w);
        dst[4]=f2bf(a1.x); dst[5]=f2bf(a1.y); dst[6]=f2bf(a1.z); dst[7]=f2bf(a1.w);
      } else {
        #pragma unroll
        for (int j = 0; j < 8; ++j){
          int k = k0 + kseg + j;
          dst[j] = (k < K) ? f2bf(Ar[k]) : (short)0;
        }
      }
    }
    // ---- W staging
    if constexpr (sizeof(WT) == 2){
      int n = bn + row;
      short8 v;
      #pragma unroll
      for (int j = 0; j < 8; ++j) v[j] = 0;
      if (n < N) v = *(const short8*)((const short*)W + (size_t)n*K + k0 + kseg);
      *(short8*)&Ws[row*40 + kseg] = v;
    } else {
      int n = bn + row;
      short* dst = &Ws[row*40 + kseg];
      if (n < N && ((K & 3) == 0) && (k0 + kseg + 8 <= K)){
        const float* Wr = (const float*)W + (size_t)n*K + k0 + kseg;
        float4 w0 = *(const float4*)Wr;
        float4 w1 = *(const float4*)(Wr + 4);
        dst[0]=f2bf(w0.x); dst[1]=f2bf(w0.y); dst[2]=f2bf(w0.z); dst[3]=f2bf(w0.w);
        dst[4]=f2bf(w1.x); dst[5]=f2bf(w1.y); dst[6]=f2bf(w1.z); dst[7]=f2bf(w1.w);
      } else {
        #pragma unroll
        for (int j = 0; j < 8; ++j){
          int k = k0 + kseg + j;
          dst[j] = (n < N && k < K) ? f2bf(((const float*)W)[(size_t)n*K + k]) : (short)0;
        }
      }
    }
    __syncthreads();
    short8 af = *(const short8*)&As[(w*16 + m16)*40 + q*8];
    #pragma unroll
    for (int j = 0; j < 4; ++j){
      short8 bfr = *(const short8*)&Ws[(j*16 + m16)*40 + q*8];
      acc[j] = __builtin_amdgcn_mfma_f32_16x16x32_bf16(af, bfr, acc[j], 0, 0, 0);
    }
    __syncthreads();
  }
  #pragma unroll
  for (int j = 0; j < 4; ++j){
    int n = bn + j*16 + m16;
    if (n < N){
      float bv = bias ? bias[n] : 0.f;
      float gv = 0.f, bbv = 0.f;
      if (ACT == 1){ gv = g[n] * BNS; bbv = bb[n]; }
      #pragma unroll
      for (int r = 0; r < 4; ++r){
        int m = bm + w*16 + q*4 + r;
        float v = acc[j][r] + bv;
        if (ACT == 1){ v = v * gv + bbv; v = fmaxf(v, 0.f); }
        C[(size_t)m*ldc + n] = v;
      }
    }
  }
}

// -------------------------------------------------- encoder max-pools
__global__ __launch_bounds__(256) void maxk_fg(float* __restrict__ f3in){
  int gg = blockIdx.x; int c = threadIdx.x;
  float m = -3e38f;
  for (int k = 0; k < Kn; ++k) m = fmaxf(m, f3in[((size_t)gg*Kn + k)*512 + 256 + c]);
  for (int k = 0; k < Kn; ++k) f3in[((size_t)gg*Kn + k)*512 + c] = m;
}

__global__ __launch_bounds__(384) void maxk_tok(const float* __restrict__ f4, float* __restrict__ tok){
  int gg = blockIdx.x; int c = threadIdx.x;
  float m = -3e38f;
  for (int k = 0; k < Kn; ++k) m = fmaxf(m, f4[((size_t)gg*Kn + k)*DM + c]);
  tok[(size_t)gg*DM + c] = m;
}

// -------------------------------------------------- pos embedding (adds into tok)
__global__ __launch_bounds__(128) void pos_kernel(const float* __restrict__ center,
                                                  const float* __restrict__ w1, const float* __restrict__ b1,
                                                  const float* __restrict__ w2, const float* __restrict__ b2,
                                                  float* __restrict__ tok){
  int gid = blockIdx.x;
  __shared__ float h1[128]; __shared__ float c3[3];
  int t = threadIdx.x;
  if (t < 3) c3[t] = center[(size_t)gid*3 + t];
  __syncthreads();
  float a = w1[t*3+0]*c3[0] + w1[t*3+1]*c3[1] + w1[t*3+2]*c3[2] + b1[t];
  h1[t] = 0.5f * a * (1.f + erff(a * 0.70710678118654752440f));
  __syncthreads();
  for (int c = t; c < DM; c += 128){
    float s = b2[c];
    for (int j = 0; j < 128; ++j) s += w2[(size_t)c*128 + j] * h1[j];
    tok[(size_t)gid*DM + c] += s;
  }
}

// -------------------------------------------------- stable argsort (rank count)
__global__ __launch_bounds__(128) void sort_kernel(const float* __restrict__ center,
                                                   int* __restrict__ order){
  int bax = blockIdx.x; int b = bax / 3, ax = bax % 3;
  __shared__ float key[128];
  int t = threadIdx.x;
  key[t] = center[(size_t)(b*Gn + t)*3 + ax];
  __syncthreads();
  float kt = key[t]; int r = 0;
  for (int j = 0; j < Gn; ++j){
    float kj = key[j];
    r += (kj < kt || (kj == kt && j < t)) ? 1 : 0;
  }
  r = min(max(r, 0), Gn-1);
  order[b*Ln + ax*Gn + r] = t;
}

// -------------------------------------------------- token gather + res init
__global__ __launch_bounds__(256) void build_h(const float* __restrict__ tok,
                        const int* __restrict__ order,
                        float* __restrict__ h, float* __restrict__ res){
  int i = blockIdx.x * blockDim.x + threadIdx.x;
  if (i >= Bn*Ln*DM) return;
  int c = i % DM; int l = (i / DM) % Ln; int b = i / (DM*Ln);
  int src = order[b*Ln + l];
  src = min(max(src, 0), Gn-1);
  h[i] = tok[((size_t)(b*Gn + src))*DM + c];
  res[i] = 0.f;
}

// -------------------------------------------------- res += h; x = LN(res)*w+b (bf16 out)
__global__ __launch_bounds__(256) void ln_res_kernel(const float* __restrict__ h,
                                                     float* __restrict__ res,
                                                     bf16* __restrict__ x,
                                                     const float* __restrict__ w,
                                                     const float* __restrict__ bias){
  int wv = threadIdx.x >> 6, ln = threadIdx.x & 63;
  int tokid = blockIdx.x*4 + wv;
  const float* hr = h + (size_t)tokid*DM;
  float* rr = res + (size_t)tokid*DM;
  bf16* xr = x + (size_t)tokid*DM;
  float v[6]; float s = 0.f;
  #pragma unroll
  for (int i = 0; i < 6; ++i){ int c = ln + 64*i; float t = hr[c] + rr[c]; rr[c] = t; v[i] = t; s += t; }
  #pragma unroll
  for (int o = 32; o > 0; o >>= 1) s += __shfl_xor(s, o);
  float mu = s * (1.f/DM);
  float q = 0.f;
  #pragma unroll
  for (int i = 0; i < 6; ++i){ float d = v[i] - mu; q += d*d; }
  #pragma unroll
  for (int o = 32; o > 0; o >>= 1) q += __shfl_xor(q, o);
  float rstd = rsqrtf(q * (1.f/DM) + EPSf);
  #pragma unroll
  for (int i = 0; i < 6; ++i){ int c = ln + 64*i;
    xr[c] = __float2bfloat16((v[i]-mu)*rstd*w[c] + bias[c]); }
}

// -------------------------------------------------- conv (big path): xz -> ucv
__global__ __launch_bounds__(256) void conv_fused(const float* __restrict__ xz,
                                                  float* __restrict__ ucv,
                                                  const float* __restrict__ cw,
                                                  const float* __restrict__ cb){
  int blk = blockIdx.x;
  int lc = blk % NLC; int bd = blk / NLC; int dch = bd % 3; int b = bd / 3;
  int t = threadIdx.x; int d = dch*256 + t;
  int l0 = lc*16;
  float w0 = cw[d*4+0], w1 = cw[d*4+1], w2 = cw[d*4+2], w3 = cw[d*4+3];
  float bias = cb[d];
  float u0 = (l0 >= 3) ? xz[((size_t)(b*Ln + l0-3))*1536 + d] : 0.f;
  float u1 = (l0 >= 2) ? xz[((size_t)(b*Ln + l0-2))*1536 + d] : 0.f;
  float u2 = (l0 >= 1) ? xz[((size_t)(b*Ln + l0-1))*1536 + d] : 0.f;
  const float* pin = xz + ((size_t)(b*Ln + l0))*1536 + d;
  float* pout = ucv + ((size_t)(b*Ln + l0))*DI + d;
  float r[16];
  #pragma unroll
  for (int i = 0; i < 16; ++i) r[i] = pin[(size_t)i*1536];
  #pragma unroll
  for (int i = 0; i < 16; ++i){
    float v = u0*w0 + u1*w1 + u2*w2 + r[i]*w3 + bias;
    pout[(size_t)i*DI] = v * fsig(v);
    u0 = u1; u1 = u2; u2 = r[i];
  }
}

// -------------------------------------------------- conv (small path): 2-pass in place
__global__ __launch_bounds__(256) void conv_save(const float* __restrict__ xz,
                                                 float* __restrict__ bnd){
  int blk = blockIdx.x;
  int lc = blk % NLC; int bd = blk / NLC; int dch = bd % 3; int b = bd / 3;
  int t = threadIdx.x; int d = dch*256 + t;
  int l0 = lc*16;
  #pragma unroll
  for (int j = 0; j < 3; ++j){
    int l = l0 - 3 + j;
    float v = (l >= 0) ? xz[((size_t)(b*Ln + l))*1536 + d] : 0.f;
    bnd[(((size_t)blk)*3 + j)*256 + t] = v;
  }
}

__global__ __launch_bounds__(256) void conv_apply(float* __restrict__ xz,
                                                  const float* __restrict__ bnd,
                                                  const float* __restrict__ cw,
                                                  const float* __restrict__ cb){
  int blk = blockIdx.x;
  int lc = blk % NLC; int bd = blk / NLC; int dch = bd % 3; int b = bd / 3;
  int t = threadIdx.x; int d = dch*256 + t;
  int l0 = lc*16;
  float w0 = cw[d*4+0], w1 = cw[d*4+1], w2 = cw[d*4+2], w3 = cw[d*4+3];
  float bias = cb[d];
  float u0 = bnd[(((size_t)blk)*3 + 0)*256 + t];
  float u1 = bnd[(((size_t)blk)*3 + 1)*256 + t];
  float u2 = bnd[(((size_t)blk)*3 + 2)*256 + t];
  float* p = xz + ((size_t)(b*Ln + l0))*1536 + d;
  float r[16];
  #pragma unroll
  for (int i = 0; i < 16; ++i) r[i] = p[(size_t)i*1536];
  #pragma unroll
  for (int i = 0; i < 16; ++i){
    float v = u0*w0 + u1*w1 + u2*w2 + r[i]*w3 + bias;
    p[(size_t)i*1536] = v * fsig(v);
    u0 = u1; u1 = u2; u2 = r[i];
  }
}

// -------------------------------------------------- chunked selective scan
__global__ __launch_bounds__(256) void scanA_kernel(const float* __restrict__ usrc, int uld,
                                                    const float* __restrict__ xdb,
                                                    const float* __restrict__ dpw,
                                                    const float* __restrict__ dpb,
                                                    const float* __restrict__ A_log,
                                                    float* __restrict__ SB_S,
                                                    float* __restrict__ SB_dt){
  __shared__ float sRow[CHS*56];
  __shared__ float sU[CHS*256];
  int blk = blockIdx.x;
  int c = blk % NCH; int bd = blk / NCH; int dch = bd % 3; int b = bd / 3;
  int t = threadIdx.x; int d = dch*256 + t;
  int l0 = c*CHS;
  for (int i = t; i < CHS*56; i += 256) sRow[i] = xdb[((size_t)(b*Ln + l0))*56 + i];
  const float* up = usrc + ((size_t)(b*Ln + l0))*uld + dch*256;
  #pragma unroll
  for (int i = 0; i < CHS; ++i) sU[i*256 + t] = up[(size_t)i*uld + t];
  float w[DTR];
  const float* wp = dpw + (size_t)d*DTR;
  #pragma unroll
  for (int j = 0; j < DTR; ++j) w[j] = wp[j];
  float a2[DSt], h[DSt];
  const float* ap = A_log + (size_t)d*DSt;
  #pragma unroll
  for (int s = 0; s < DSt; ++s){ a2[s] = -__expf(ap[s]) * LOG2E; h[s] = 0.f; }
  float dbias = dpb[d];
  float sumdt = 0.f;
  __syncthreads();
  for (int i = 0; i < CHS; ++i){
    int ro = i*56;
    float dtr = dbias;
    #pragma unroll
    for (int j = 0; j < DTR; ++j) dtr += w[j] * sRow[ro + j];
    float dtv = fsoftplus(dtr);
    sumdt += dtv;
    float du = dtv * sU[i*256 + t];
    #pragma unroll
    for (int s = 0; s < DSt; ++s)
      h[s] = exp2f(dtv * a2[s]) * h[s] + du * sRow[ro + 24 + s];
  }
  size_t sb = ((size_t)blk*256 + t)*16;
  #pragma unroll
  for (int s = 0; s < DSt; ++s) SB_S[sb + s] = h[s];
  SB_dt[(size_t)blk*256 + t] = sumdt;
}

__global__ __launch_bounds__(256) void scanB_kernel(float* __restrict__ xz,
                                                    const float* __restrict__ usrc, int uld,
                                                    const float* __restrict__ xdb,
                                                    const float* __restrict__ dpw,
                                                    const float* __restrict__ dpb,
                                                    const float* __restrict__ A_log,
                                                    const float* __restrict__ Dp,
                                                    const float* __restrict__ SB_S,
                                                    const float* __restrict__ SB_dt){
  __shared__ float sRow[CHS*56];
  __shared__ float sU[CHS*256];
  int blk = blockIdx.x;
  int c = blk % NCH; int bd = blk / NCH; int dch = bd % 3; int b = bd / 3;
  int t = threadIdx.x; int d = dch*256 + t;
  int l0 = c*CHS;
  for (int i = t; i < CHS*56; i += 256) sRow[i] = xdb[((size_t)(b*Ln + l0))*56 + i];
  const float* up = usrc + ((size_t)(b*Ln + l0))*uld + dch*256;
  #pragma unroll
  for (int i = 0; i < CHS; ++i) sU[i*256 + t] = up[(size_t)i*uld + t];
  float w[DTR];
  const float* wp = dpw + (size_t)d*DTR;
  #pragma unroll
  for (int j = 0; j < DTR; ++j) w[j] = wp[j];
  float a2[DSt], h[DSt];
  const float* ap = A_log + (size_t)d*DSt;
  #pragma unroll
  for (int s = 0; s < DSt; ++s){ a2[s] = -__expf(ap[s]) * LOG2E; h[s] = 0.f; }
  for (int cc = 0; cc < c; ++cc){
    size_t base = (((size_t)bd*NCH + cc)*256 + t)*16;
    float sd = SB_dt[((size_t)bd*NCH + cc)*256 + t];
    #pragma unroll
    for (int s = 0; s < DSt; ++s)
      h[s] = exp2f(sd * a2[s]) * h[s] + SB_S[base + s];
  }
  float dbias = dpb[d];
  float Dd = Dp[d];
  float* ydst = xz + ((size_t)(b*Ln + l0))*1536 + dch*256;
  __syncthreads();
  for (int i = 0; i < CHS; ++i){
    int ro = i*56;
    float dtr = dbias;
    #pragma unroll
    for (int j = 0; j < DTR; ++j) dtr += w[j] * sRow[ro + j];
    float dtv = fsoftplus(dtr);
    float u = sU[i*256 + t];
    float du = dtv * u;
    float yv = 0.f;
    #pragma unroll
    for (int s = 0; s < DSt; ++s){
      h[s] = exp2f(dtv * a2[s]) * h[s] + du * sRow[ro + 24 + s];
      yv += h[s] * sRow[ro + 40 + s];
    }
    ydst[(size_t)i*1536 + t] = yv + u*Dd;
  }
}

// -------------------------------------------------- final two LayerNorms
__global__ __launch_bounds__(256) void final_ln_kernel(const float* __restrict__ h,
                                                       const float* __restrict__ res,
                                                       const float* w1, const float* b1,
                                                       const float* w2, const float* b2,
                                                       float* __restrict__ x){
  int wv = threadIdx.x >> 6, ln = threadIdx.x & 63;
  int tokid = blockIdx.x*4 + wv;
  const float* hr = h + (size_t)tokid*DM;
  const float* rr = res + (size_t)tokid*DM;
  float* xr = x + (size_t)tokid*DM;
  float v[6]; float s = 0.f;
  #pragma unroll
  for (int i = 0; i < 6; ++i){ int c = ln + 64*i; v[i] = hr[c] + rr[c]; s += v[i]; }
  #pragma unroll
  for (int o = 32; o > 0; o >>= 1) s += __shfl_xor(s, o);
  float mu = s * (1.f/DM); float q = 0.f;
  #pragma unroll
  for (int i = 0; i < 6; ++i){ float dd = v[i]-mu; q += dd*dd; }
  #pragma unroll
  for (int o = 32; o > 0; o >>= 1) q += __shfl_xor(q, o);
  float rstd = rsqrtf(q * (1.f/DM) + EPSf);
  float u[6]; float s2 = 0.f;
  #pragma unroll
  for (int i = 0; i < 6; ++i){ int c = ln + 64*i; u[i] = (v[i]-mu)*rstd*w1[c] + b1[c]; s2 += u[i]; }
  #pragma unroll
  for (int o = 32; o > 0; o >>= 1) s2 += __shfl_xor(s2, o);
  float mu2 = s2 * (1.f/DM); float q2 = 0.f;
  #pragma unroll
  for (int i = 0; i < 6; ++i){ float dd = u[i]-mu2; q2 += dd*dd; }
  #pragma unroll
  for (int o = 32; o > 0; o >>= 1) q2 += __shfl_xor(q2, o);
  float rstd2 = rsqrtf(q2 * (1.f/DM) + EPSf);
  #pragma unroll
  for (int i = 0; i < 6; ++i){ int c = ln + 64*i; xr[c] = (u[i]-mu2)*rstd2*w2[c] + b2[c]; }
}

// -------------------------------------------------- mean over L + MLP head
__global__ __launch_bounds__(384) void head_kernel(const float* __restrict__ x,
    const float* w1, const float* b1, const float* g1, const float* bb1,
    const float* w2, const float* b2, const float* g2, const float* bb2,
    const float* w3, const float* b3, float* __restrict__ out){
  int b = blockIdx.x; int t = threadIdx.x;
  __shared__ float feat[DM]; __shared__ float h1[256]; __shared__ float h2[256];
  float s = 0.f;
  for (int l = 0; l < Ln; ++l) s += x[((size_t)(b*Ln + l))*DM + t];
  feat[t] = s * (1.f/Ln);
  __syncthreads();
  if (t < 256){
    float a = b1[t];
    for (int j = 0; j < DM; ++j) a += w1[(size_t)t*DM + j] * feat[j];
    a = a * (g1[t] * BNS) + bb1[t];
    h1[t] = fmaxf(a, 0.f);
  }
  __syncthreads();
  if (t < 256){
    float a = b2[t];
    for (int j = 0; j < 256; ++j) a += w2[(size_t)t*256 + j] * h1[j];
    a = a * (g2[t] * BNS) + bb2[t];
    h2[t] = fmaxf(a, 0.f);
  }
  __syncthreads();
  if (t < CLSn){
    float a = b3[t];
    for (int j = 0; j < 256; ++j) a += w3[(size_t)t*256 + j] * h2[j];
    out[b*CLSn + t] = a;
  }
}

extern "C" void kernel_launch(void* const* d_in, const int* in_sizes, int n_in,
                              void* d_out, int out_size, void* d_ws, size_t ws_size,
                              hipStream_t stream) {
  if (n_in < 42) return;
  if (out_size < Bn*CLSn) return;
  constexpr size_t WS_FLOATS = 3919936;
  if (ws_size < WS_FLOATS * sizeof(float)) return;
  constexpr size_t MIDF = 5812224;          // bf16 weight cache (floats)
  constexpr size_t BIGF = 18874368;         // encoder F3in/F3/F1
  const bool mid = ws_size >= (WS_FLOATS + MIDF) * sizeof(float);
  const bool big = ws_size >= (WS_FLOATS + MIDF + BIGF) * sizeof(float);

  const float* pts       = (const float*)d_in[0];
  const float* enc_w1    = (const float*)d_in[1];  const float* enc_b1    = (const float*)d_in[2];
  const float* enc_bn1_g = (const float*)d_in[3];  const float* enc_bn1_b = (const float*)d_in[4];
  const float* enc_w2    = (const float*)d_in[5];  const float* enc_b2    = (const float*)d_in[6];
  const float* enc_w3    = (const float*)d_in[7];  const float* enc_b3    = (const float*)d_in[8];
  const float* enc_bn2_g = (const float*)d_in[9];  const float* enc_bn2_b = (const float*)d_in[10];
  const float* enc_w4    = (const float*)d_in[11]; const float* enc_b4    = (const float*)d_in[12];
  const float* pos_w1    = (const float*)d_in[13]; const float* pos_b1    = (const float*)d_in[14];
  const float* pos_w2    = (const float*)d_in[15]; const float* pos_b2    = (const float*)d_in[16];
  const float* ln_w      = (const float*)d_in[17]; const float* ln_b      = (const float*)d_in[18];
  const float* in_proj_w = (const float*)d_in[19];
  const float* conv_w    = (const float*)d_in[20]; const float* conv_b    = (const float*)d_in[21];
  const float* x_proj_w  = (const float*)d_in[22];
  const float* dt_proj_w = (const float*)d_in[23]; const float* dt_proj_b = (const float*)d_in[24];
  const float* A_log     = (const float*)d_in[25]; const float* D_param   = (const float*)d_in[26];
  const float* out_proj_w= (const float*)d_in[27];
  const float* normf_w   = (const float*)d_in[28]; const float* normf_b   = (const float*)d_in[29];
  const float* norm_w    = (const float*)d_in[30]; const float* norm_b    = (const float*)d_in[31];
  const float* head_w1   = (const float*)d_in[32]; const float* head_b1   = (const float*)d_in[33];
  const float* head_bn1_g= (const float*)d_in[34]; const float* head_bn1_b= (const float*)d_in[35];
  const float* head_w2   = (const float*)d_in[36]; const float* head_b2   = (const float*)d_in[37];
  const float* head_bn2_g= (const float*)d_in[38]; const float* head_bn2_b= (const float*)d_in[39];
  const float* head_w3   = (const float*)d_in[40]; const float* head_b3   = (const float*)d_in[41];

  float* ws = (float*)d_ws;
  float* hb   = ws;                   // 589,824 floats
  float* resb = ws + 589824;          // 589,824
  float* U    = ws + 1179648;         // 2,740,224
  // setup/encoder view of U
  float* center = U;
  float* nb     = U + 1536;
  float* tok    = U + 50688;
  int*   order  = (int*)(U + 247296);
  float* eb0    = U + 262144;
  float* eb1    = U + 1310720;
  // mamba view of U
  float* xz   = U;                      // 2,359,296 (1536 x 1536)
  float* xdb  = U + 2359296;            // 86,016
  bf16*  xb   = (bf16*)(U + 2445312);   // 589,824 bf16
  float* SBdt = U + 2445312;            // 36,864 (xb dead when scanA runs)
  float* BND  = U + 2482176;            // 221,184
  float* SBS  = hb;                     // hb dead between ln_res and out_proj
  float* xf   = U;
  // mid tier: bf16 weight cache
  float* WB = ws + WS_FLOATS;
  bf16* wb_ip = (bf16*)WB;                  // 12x1536x384
  bf16* wb_op = (bf16*)(WB + 3538944);      // 12x384x768
  bf16* wb_xp = (bf16*)(WB + 5308416);      // 12x56x768
  bf16* wb_e2 = (bf16*)(WB + 5566464);      // 256x128
  bf16* wb_e3 = (bf16*)(WB + 5582848);      // 512x512
  bf16* wb_e4 = (bf16*)(WB + 5713920);      // 384x512
  // big tier buffers
  float* F3in = WB + MIDF;                  // 8,388,608 (16384 x 512)
  float* F3   = WB + MIDF + 8388608;
  float* F1   = WB + MIDF + 16777216;
  float* F4   = F3in;
  float* ucv  = F3in;                       // 1536x768 reuse after encoder

  if (mid){
    cvt_bf16<<<(12*1536*384/4 + 255)/256, 256, 0, stream>>>(in_proj_w, wb_ip, 12*1536*384);
    cvt_bf16<<<(12*384*768/4 + 255)/256, 256, 0, stream>>>(out_proj_w, wb_op, 12*384*768);
    cvt_bf16<<<(12*56*768/4 + 255)/256, 256, 0, stream>>>(x_proj_w, wb_xp, 12*56*768);
    cvt_bf16<<<(256*128/4 + 255)/256, 256, 0, stream>>>(enc_w2, wb_e2, 256*128);
    cvt_bf16<<<(512*512/4 + 255)/256, 256, 0, stream>>>(enc_w3, wb_e3, 512*512);
    cvt_bf16<<<(384*512/4 + 255)/256, 256, 0, stream>>>(enc_w4, wb_e4, 384*512);
  }

  fps_kernel<<<Bn, 64, 0, stream>>>(pts, center);
  knn_kernel<<<Bn*Gn, 256, 0, stream>>>(pts, center, nb);

  if (big){
    gemm_mfma<float,float,1,0><<<dim3(256,2), 256, 0, stream>>>(nb, 3, enc_w1, enc_b1,
        enc_bn1_g, enc_bn1_b, F1, 128, 16384, 128, 3);
    gemm_mfma<float,bf16,0,0><<<dim3(256,4), 256, 0, stream>>>(F1, 128, wb_e2, enc_b2,
        nullptr, nullptr, F3in + 256, 512, 16384, 256, 128);
    maxk_fg<<<512, 256, 0, stream>>>(F3in);
    gemm_mfma<float,bf16,1,0><<<dim3(256,8), 256, 0, stream>>>(F3in, 512, wb_e3, enc_b3,
        enc_bn2_g, enc_bn2_b, F3, 512, 16384, 512, 512);
    gemm_mfma<float,bf16,0,0><<<dim3(256,6), 256, 0, stream>>>(F3, 512, wb_e4, enc_b4,
        nullptr, nullptr, F4, 384, 16384, 384, 512);
    maxk_tok<<<512, 384, 0, stream>>>(F4, tok);
  } else {
    for (int ch = 0; ch < 8; ++ch){
      const float* nb_c = nb + (size_t)ch*2048*3;
      float* tok_c = tok + (size_t)ch*64*DM;
      gemm_mfma<float,float,1,0><<<dim3(32,2), 256, 0, stream>>>(nb_c, 3, enc_w1, enc_b1,
          enc_bn1_g, enc_bn1_b, eb1, 128, 2048, 128, 3);
      if (mid){
        gemm_mfma<float,bf16,0,0><<<dim3(32,4), 256, 0, stream>>>(eb1, 128, wb_e2, enc_b2,
            nullptr, nullptr, eb0 + 256, 512, 2048, 256, 128);
        maxk_fg<<<64, 256, 0, stream>>>(eb0);
        gemm_mfma<float,bf16,1,0><<<dim3(32,8), 256, 0, stream>>>(eb0, 512, wb_e3, enc_b3,
            enc_bn2_g, enc_bn2_b, eb1, 512, 2048, 512, 512);
        gemm_mfma<float,bf16,0,0><<<dim3(32,6), 256, 0, stream>>>(eb1, 512, wb_e4, enc_b4,
            nullptr, nullptr, eb0, 384, 2048, 384, 512);
      } else {
        gemm_mfma<float,float,0,0><<<dim3(32,4), 256, 0, stream>>>(eb1, 128, enc_w2, enc_b2,
            nullptr, nullptr, eb0 + 256, 512, 2048, 256, 128);
        maxk_fg<<<64, 256, 0, stream>>>(eb0);
        gemm_mfma<float,float,1,0><<<dim3(32,8), 256, 0, stream>>>(eb0, 512, enc_w3, enc_b3,
            enc_bn2_g, enc_bn2_b, eb1, 512, 2048, 512, 512);
        gemm_mfma<float,float,0,0><<<dim3(32,6), 256, 0, stream>>>(eb1, 512, enc_w4, enc_b4,
            nullptr, nullptr, eb0, 384, 2048, 384, 512);
      }
      maxk_tok<<<64, 384, 0, stream>>>(eb0, tok_c);
    }
  }

  pos_kernel<<<Bn*Gn, 128, 0, stream>>>(center, pos_w1, pos_b1, pos_w2, pos_b2, tok);
  sort_kernel<<<Bn*3, 128, 0, stream>>>(center, order);
  build_h<<<(Bn*Ln*DM + 255)/256, 256, 0, stream>>>(tok, order, hb, resb);

  for (int l = 0; l < DEPTH; ++l){
    const float* lnw  = ln_w      + (size_t)l*DM;
    const float* lnb  = ln_b      + (size_t)l*DM;
    const float* ipw  = in_proj_w + (size_t)l*1536*DM;
    const float* cw   = conv_w    + (size_t)l*DI*4;
    const float* cb   = conv_b    + (size_t)l*DI;
    const float* xpw  = x_proj_w  + (size_t)l*56*DI;
    const float* dpw  = dt_proj_w + (size_t)l*DI*DTR;
    const float* dpb  = dt_proj_b + (size_t)l*DI;
    const float* Alg  = A_log     + (size_t)l*DI*DSt;
    const float* Dpar = D_param   + (size_t)l*DI;
    const float* opw  = out_proj_w+ (size_t)l*DM*DI;

    ln_res_kernel<<<Bn*Ln/4, 256, 0, stream>>>(hb, resb, xb, lnw, lnb);
    if (mid){
      gemm_mfma<bf16,bf16,0,0><<<dim3(24,24), 256, 0, stream>>>(xb, DM,
          wb_ip + (size_t)l*1536*DM, nullptr, nullptr, nullptr, xz, 1536, Bn*Ln, 1536, DM);
    } else {
      gemm_mfma<bf16,float,0,0><<<dim3(24,24), 256, 0, stream>>>(xb, DM, ipw,
          nullptr, nullptr, nullptr, xz, 1536, Bn*Ln, 1536, DM);
    }
    if (big){
      conv_fused<<<Bn*3*NLC, 256, 0, stream>>>(xz, ucv, cw, cb);
      if (mid)
        gemm_mfma<float,bf16,0,0><<<dim3(24,1), 256, 0, stream>>>(ucv, DI,
            wb_xp + (size_t)l*56*DI, nullptr, nullptr, nullptr, xdb, 56, Bn*Ln, 56, DI);
      else
        gemm_mfma<float,float,0,0><<<dim3(24,1), 256, 0, stream>>>(ucv, DI, xpw,
            nullptr, nullptr, nullptr, xdb, 56, Bn*Ln, 56, DI);
      scanA_kernel<<<Bn*3*NCH, 256, 0, stream>>>(ucv, DI, xdb, dpw, dpb, Alg, SBS, SBdt);
      scanB_kernel<<<Bn*3*NCH, 256, 0, stream>>>(xz, ucv, DI, xdb, dpw, dpb, Alg, Dpar, SBS, SBdt);
    } else {
      conv_save<<<Bn*3*NLC, 256, 0, stream>>>(xz, BND);
      conv_apply<<<Bn*3*NLC, 256, 0, stream>>>(xz, BND, cw, cb);
      if (mid)
        gemm_mfma<float,bf16,0,0><<<dim3(24,1), 256, 0, stream>>>(xz, 1536,
            wb_xp + (size_t)l*56*DI, nullptr, nullptr, nullptr, xdb, 56, Bn*Ln, 56, DI);
      else
        gemm_mfma<float,float,0,0><<<dim3(24,1), 256, 0, stream>>>(xz, 1536, xpw,
            nullptr, nullptr, nullptr, xdb, 56, Bn*Ln, 56, DI);
      scanA_kernel<<<Bn*3*NCH, 256, 0, stream>>>(xz, 1536, xdb, dpw, dpb, Alg, SBS, SBdt);
      scanB_kernel<<<Bn*3*NCH, 256, 0, stream>>>(xz, xz, 1536, xdb, dpw, dpb, Alg, Dpar, SBS, SBdt);
    }
    if (mid){
      gemm_mfma<float,bf16,0,1><<<dim3(24,6), 256, 0, stream>>>(xz, 1536,
          wb_op + (size_t)l*DM*DI, nullptr, nullptr, nullptr, hb, DM, Bn*Ln, DM, DI);
    } else {
      gemm_mfma<float,float,0,1><<<dim3(24,6), 256, 0, stream>>>(xz, 1536, opw,
          nullptr, nullptr, nullptr, hb, DM, Bn*Ln, DM, DI);
    }
  }

  final_ln_kernel<<<Bn*Ln/4, 256, 0, stream>>>(hb, resb, normf_w, normf_b, norm_w, norm_b, xf);
  head_kernel<<<Bn, 384, 0, stream>>>(xf, head_w1, head_b1, head_bn1_g, head_bn1_b,
                                      head_w2, head_b2, head_bn2_g, head_bn2_b,
                                      head_w3, head_b3, (float*)d_out);
}